// Round 1
// baseline (723.644 us; speedup 1.0000x reference)
//
#include <hip/hip_runtime.h>

typedef __attribute__((ext_vector_type(4))) float floatx4;
typedef __attribute__((ext_vector_type(8))) _Float16 half8;
typedef __attribute__((ext_vector_type(4))) _Float16 half4;

#define TT 2048
#define HIDDEN 2048
#define NH 32
#define NKV 8
#define HD 128
#define QSIZE 4096
#define KVSIZE 1024
#define QKVN 6144
#define WINDOW 512

// ---------------- fp32 -> fp16 convert ----------------
__global__ __launch_bounds__(256) void cvt_f32_f16_kernel(const float* __restrict__ in,
                                                          _Float16* __restrict__ out) {
  int i = (blockIdx.x * 256 + threadIdx.x) * 4;
  float4 v = *(const float4*)&in[i];
  alignas(8) _Float16 o[4] = {(_Float16)v.x, (_Float16)v.y, (_Float16)v.z, (_Float16)v.w};
  *(uint2*)&out[i] = *(const uint2*)o;
}

// ---------------- fp32 [R][C] -> fp16 [C][R] transpose ----------------
__global__ __launch_bounds__(256) void transpose_f32_f16_kernel(
    const float* __restrict__ in, _Float16* __restrict__ out, int R, int C) {
  __shared__ float tile[32][33];
  int bc = blockIdx.x * 32;
  int br = blockIdx.y * 32;
  int c = threadIdx.x & 31;
  int r0 = threadIdx.x >> 5;  // 0..7
#pragma unroll
  for (int i = 0; i < 4; ++i) {
    int r = r0 + 8 * i;
    tile[r][c] = in[(size_t)(br + r) * C + bc + c];
  }
  __syncthreads();
#pragma unroll
  for (int i = 0; i < 4; ++i) {
    int r = r0 + 8 * i;
    out[(size_t)(bc + r) * R + br + c] = (_Float16)tile[c][r];
  }
}

// ---------------- MFMA GEMM: C[M][N] = A[M][K] * Bt[N][K]^T ----------------
// A, Bt fp16 row-major; C OutT. M,N multiples of 128; K multiple of 32.
template <typename OutT>
__global__ __launch_bounds__(256, 2) void gemm_bt_kernel(
    const _Float16* __restrict__ A, const _Float16* __restrict__ Bt,
    OutT* __restrict__ C, int M, int N, int K) {
  __shared__ _Float16 As[128 * 32];
  __shared__ _Float16 Bs[128 * 32];
  int tid = threadIdx.x;
  int wave = tid >> 6, lane = tid & 63;
  int wm = wave >> 1, wn = wave & 1;
  int m0 = blockIdx.y * 128, n0 = blockIdx.x * 128;
  int lr = lane & 15;
  int kq = (lane >> 4) * 8;
  floatx4 acc[4][4];
#pragma unroll
  for (int i = 0; i < 4; ++i)
#pragma unroll
    for (int j = 0; j < 4; ++j) acc[i][j] = (floatx4){0.f, 0.f, 0.f, 0.f};

  for (int k0 = 0; k0 < K; k0 += 32) {
    __syncthreads();
#pragma unroll
    for (int it = 0; it < 2; ++it) {
      int c = tid + it * 256;           // 512 chunks of 8 halfs per tile
      int row = c >> 2, kp = (c & 3) * 8;
      *(uint4*)&As[row * 32 + kp] = *(const uint4*)&A[(size_t)(m0 + row) * K + k0 + kp];
      *(uint4*)&Bs[row * 32 + kp] = *(const uint4*)&Bt[(size_t)(n0 + row) * K + k0 + kp];
    }
    __syncthreads();
    half8 a[4], b[4];
#pragma unroll
    for (int i = 0; i < 4; ++i) a[i] = *(const half8*)&As[(wm * 64 + i * 16 + lr) * 32 + kq];
#pragma unroll
    for (int j = 0; j < 4; ++j) b[j] = *(const half8*)&Bs[(wn * 64 + j * 16 + lr) * 32 + kq];
#pragma unroll
    for (int i = 0; i < 4; ++i)
#pragma unroll
      for (int j = 0; j < 4; ++j)
        acc[i][j] = __builtin_amdgcn_mfma_f32_16x16x32_f16(a[i], b[j], acc[i][j], 0, 0, 0);
  }
  int rq = (lane >> 4) * 4;
#pragma unroll
  for (int i = 0; i < 4; ++i)
#pragma unroll
    for (int j = 0; j < 4; ++j)
#pragma unroll
      for (int r = 0; r < 4; ++r) {
        int row = m0 + wm * 64 + i * 16 + rq + r;
        int col = n0 + wn * 64 + j * 16 + lr;
        C[(size_t)row * N + col] = (OutT)acc[i][j][r];
      }
}

// ---------------- per-head RMSNorm + RoPE (wave per row) ----------------
__global__ __launch_bounds__(256) void normrope_kernel(
    const _Float16* __restrict__ qkv, const float* __restrict__ qw,
    const float* __restrict__ kw, const int* __restrict__ positions,
    _Float16* __restrict__ qh, _Float16* __restrict__ khb) {
  int wid = blockIdx.x * 4 + (threadIdx.x >> 6);  // 0 .. 81919
  int lane = threadIdx.x & 63;
  int t, hh;
  const _Float16* src;
  _Float16* dst;
  const float* w;
  if (wid < TT * NH) {
    t = wid >> 5; hh = wid & 31;
    src = qkv + (size_t)t * QKVN + hh * HD;
    dst = qh + ((size_t)t * NH + hh) * HD;
    w = qw;
  } else {
    int r = wid - TT * NH;
    t = r >> 3; hh = r & 7;
    src = qkv + (size_t)t * QKVN + QSIZE + hh * HD;
    dst = khb + ((size_t)t * NKV + hh) * HD;
    w = kw;
  }
  float x1 = (float)src[lane];
  float x2 = (float)src[lane + 64];
  float ss = x1 * x1 + x2 * x2;
#pragma unroll
  for (int off = 1; off < 64; off <<= 1) ss += __shfl_xor(ss, off);
  float rr = rsqrtf(ss * (1.0f / 128.0f) + 1e-6f);
  float n1 = x1 * rr * w[lane];
  float n2 = x2 * rr * w[lane + 64];
  float pos = (float)positions[t];
  float invf = exp2f(-(float)lane * (13.287712379549449f / 64.0f));  // 10000^(-lane/64)
  float ang = pos * invf;
  float sn, cs;
  sincosf(ang, &sn, &cs);
  dst[lane] = (_Float16)(n1 * cs - n2 * sn);
  dst[lane + 64] = (_Float16)(n2 * cs + n1 * sn);
}

// ---------------- gate = softplus(hidden @ w_g), 4 rows per block ----------------
__global__ __launch_bounds__(256) void gate_kernel(const float* __restrict__ hs,
                                                   const float* __restrict__ wg,
                                                   float* __restrict__ gate) {
  __shared__ float hrow[4][HIDDEN];
  __shared__ float red[4][8][32];
  int tid = threadIdx.x;
  int tb = blockIdx.x * 4;
  for (int c = tid; c < 4 * (HIDDEN / 4); c += 256) {
    int r = c >> 9, off = (c & 511) * 4;
    *(float4*)&hrow[r][off] = *(const float4*)&hs[(size_t)(tb + r) * HIDDEN + off];
  }
  __syncthreads();
  int hcol = tid & 31, part = tid >> 5;
  float p0 = 0.f, p1 = 0.f, p2 = 0.f, p3 = 0.f;
  for (int i = 0; i < 256; ++i) {
    int k = part * 256 + i;
    float w = wg[(size_t)k * NH + hcol];
    p0 += hrow[0][k] * w; p1 += hrow[1][k] * w;
    p2 += hrow[2][k] * w; p3 += hrow[3][k] * w;
  }
  red[0][part][hcol] = p0; red[1][part][hcol] = p1;
  red[2][part][hcol] = p2; red[3][part][hcol] = p3;
  __syncthreads();
  if (tid < 128) {
    int r = tid >> 5, hc = tid & 31;
    float s = 0.f;
#pragma unroll
    for (int p = 0; p < 8; ++p) s += red[r][p][hc];
    float sp = (s > 0.f) ? s + log1pf(expf(-s)) : log1pf(expf(s));
    gate[(size_t)(tb + r) * NH + hc] = sp;
  }
}

// ---------------- sliding-window flash attention (VALU) ----------------
#define LW 132  // padded LDS row stride in halfs (264 B: 8B-aligned, <=2-way bank conflicts)
__global__ __launch_bounds__(256, 2) void attn_kernel(
    const _Float16* __restrict__ Qh, const _Float16* __restrict__ Kh,
    const _Float16* __restrict__ QKVh, const float* __restrict__ gate,
    const int* __restrict__ positions, _Float16* __restrict__ Og) {
  __shared__ _Float16 Qs[64 * LW];
  __shared__ _Float16 Ks[64 * LW];
  __shared__ _Float16 Vs[64 * LW];
  __shared__ _Float16 Ps[64 * 64];
  const float scale = 0.08838834764831845f;  // 128^-0.5
  int tid = threadIdx.x;
  int qt = blockIdx.x, h = blockIdx.y;
  int kh = h >> 2;
  int t0 = qt * 64;
  int qr = tid >> 4;  // 0..15 (q rows qr*4..qr*4+3) -- rows of a wave stay in that wave
  int sc = tid & 15;  // key-slice / d-slice index

  // stage Q tile (64 x 128) once
  for (int c = tid; c < 2048; c += 256) {
    int row = c >> 5, part = c & 31;
    *(uint2*)&Qs[row * LW + part * 4] =
        *(const uint2*)&Qh[((size_t)(t0 + row) * NH + h) * HD + part * 4];
  }
  int pq[4];
#pragma unroll
  for (int i = 0; i < 4; ++i) pq[i] = positions[t0 + qr * 4 + i];

  float O[4][8];
  float m_i[4], l_i[4];
#pragma unroll
  for (int i = 0; i < 4; ++i) {
    m_i[i] = -1e30f; l_i[i] = 0.f;
#pragma unroll
    for (int d = 0; d < 8; ++d) O[i][d] = 0.f;
  }

  int lo = t0 - (WINDOW - 1);
  if (lo < 0) lo = 0;
  int st0 = lo >> 6;
  for (int st = st0; st <= qt; ++st) {
    __syncthreads();  // prior PV / Q-stage complete before restage
    for (int c = tid; c < 2048; c += 256) {
      int row = c >> 5, part = c & 31;
      int s = st * 64 + row;
      *(uint2*)&Ks[row * LW + part * 4] =
          *(const uint2*)&Kh[((size_t)s * NKV + kh) * HD + part * 4];
      *(uint2*)&Vs[row * LW + part * 4] =
          *(const uint2*)&QKVh[(size_t)s * QKVN + QSIZE + KVSIZE + kh * HD + part * 4];
    }
    __syncthreads();

    // QK^T: thread computes 4q x 4s (s strided by 16 for conflict-free LDS)
    float acc[4][4];
#pragma unroll
    for (int i = 0; i < 4; ++i)
#pragma unroll
      for (int j = 0; j < 4; ++j) acc[i][j] = 0.f;

    for (int d = 0; d < 128; d += 4) {
      float qv[4][4], kv[4][4];
#pragma unroll
      for (int i = 0; i < 4; ++i) {
        half4 q4 = *(const half4*)&Qs[(qr * 4 + i) * LW + d];
#pragma unroll
        for (int dd = 0; dd < 4; ++dd) qv[i][dd] = (float)q4[dd];
      }
#pragma unroll
      for (int j = 0; j < 4; ++j) {
        half4 k4 = *(const half4*)&Ks[(sc + 16 * j) * LW + d];
#pragma unroll
        for (int dd = 0; dd < 4; ++dd) kv[j][dd] = (float)k4[dd];
      }
#pragma unroll
      for (int i = 0; i < 4; ++i)
#pragma unroll
        for (int j = 0; j < 4; ++j)
#pragma unroll
          for (int dd = 0; dd < 4; ++dd) acc[i][j] += qv[i][dd] * kv[j][dd];
    }

    int ps[4];
#pragma unroll
    for (int j = 0; j < 4; ++j) ps[j] = positions[st * 64 + sc + 16 * j];

    // mask + online softmax (row state replicated across the 16 lanes of group qr)
#pragma unroll
    for (int i = 0; i < 4; ++i) {
      float rmax = -1e30f;
#pragma unroll
      for (int j = 0; j < 4; ++j) {
        int diff = pq[i] - ps[j];
        bool ok = (diff >= 0) && (diff < WINDOW);
        float v = ok ? acc[i][j] * scale : -1e30f;
        acc[i][j] = v;
        rmax = fmaxf(rmax, v);
      }
#pragma unroll
      for (int off = 1; off < 16; off <<= 1) rmax = fmaxf(rmax, __shfl_xor(rmax, off));
      float mnew = fmaxf(m_i[i], rmax);
      float alpha = __expf(m_i[i] - mnew);
      float psum = 0.f;
      float pv[4];
#pragma unroll
      for (int j = 0; j < 4; ++j) {
        float p = (acc[i][j] > -1e29f) ? __expf(acc[i][j] - mnew) : 0.f;
        pv[j] = p;
        psum += p;
      }
#pragma unroll
      for (int off = 1; off < 16; off <<= 1) psum += __shfl_xor(psum, off);
      m_i[i] = mnew;
      l_i[i] = l_i[i] * alpha + psum;
#pragma unroll
      for (int d = 0; d < 8; ++d) O[i][d] *= alpha;
#pragma unroll
      for (int j = 0; j < 4; ++j) Ps[(qr * 4 + i) * 64 + sc + 16 * j] = (_Float16)pv[j];
    }
    __syncthreads();

    // PV: thread accumulates 4q x 8d (d cols sc*8..sc*8+7)
    for (int s = 0; s < 64; ++s) {
      half4 va = *(const half4*)&Vs[s * LW + sc * 8];
      half4 vb = *(const half4*)&Vs[s * LW + sc * 8 + 4];
      float vf[8];
#pragma unroll
      for (int dd = 0; dd < 4; ++dd) {
        vf[dd] = (float)va[dd];
        vf[4 + dd] = (float)vb[dd];
      }
#pragma unroll
      for (int i = 0; i < 4; ++i) {
        float p = (float)Ps[(qr * 4 + i) * 64 + s];
#pragma unroll
        for (int dd = 0; dd < 8; ++dd) O[i][dd] += p * vf[dd];
      }
    }
  }

  // epilogue: normalize, gate, write fp16
#pragma unroll
  for (int i = 0; i < 4; ++i) {
    int t = t0 + qr * 4 + i;
    float g = gate[(size_t)t * NH + h];
    float inv = g / l_i[i];
    alignas(16) _Float16 tmp[8];
#pragma unroll
    for (int dd = 0; dd < 8; ++dd) tmp[dd] = (_Float16)(O[i][dd] * inv);
    *(uint4*)&Og[(size_t)t * QSIZE + h * HD + sc * 8] = *(const uint4*)tmp;
  }
}

// ---------------- launcher ----------------
extern "C" void kernel_launch(void* const* d_in, const int* in_sizes, int n_in,
                              void* d_out, int out_size, void* d_ws, size_t ws_size,
                              hipStream_t stream) {
  const int* positions = (const int*)d_in[0];
  const float* hidden = (const float*)d_in[1];
  const float* w_qkv = (const float*)d_in[2];
  const float* w_o = (const float*)d_in[3];
  const float* w_g = (const float*)d_in[4];
  const float* q_norm_w = (const float*)d_in[5];
  const float* k_norm_w = (const float*)d_in[6];
  float* out = (float*)d_out;

  char* ws = (char*)d_ws;
  size_t off = 0;
  auto alloc = [&](size_t bytes) {
    void* p = ws + off;
    off += (bytes + 255) & ~(size_t)255;
    return p;
  };
  _Float16* Xb = (_Float16*)alloc((size_t)TT * HIDDEN * 2);
  _Float16* Wqkvt = (_Float16*)alloc((size_t)QKVN * HIDDEN * 2);
  _Float16* Wot = (_Float16*)alloc((size_t)HIDDEN * QSIZE * 2);
  _Float16* QKVh = (_Float16*)alloc((size_t)TT * QKVN * 2);
  _Float16* Qh = (_Float16*)alloc((size_t)TT * NH * HD * 2);
  _Float16* Kh = (_Float16*)alloc((size_t)TT * NKV * HD * 2);
  float* gate = (float*)alloc((size_t)TT * NH * 4);
  _Float16* Og = (_Float16*)alloc((size_t)TT * QSIZE * 2);

  cvt_f32_f16_kernel<<<(TT * HIDDEN) / 1024, 256, 0, stream>>>(hidden, Xb);
  transpose_f32_f16_kernel<<<dim3(QKVN / 32, HIDDEN / 32), 256, 0, stream>>>(w_qkv, Wqkvt,
                                                                             HIDDEN, QKVN);
  transpose_f32_f16_kernel<<<dim3(HIDDEN / 32, QSIZE / 32), 256, 0, stream>>>(w_o, Wot, QSIZE,
                                                                              HIDDEN);
  gemm_bt_kernel<_Float16><<<dim3(QKVN / 128, TT / 128), 256, 0, stream>>>(Xb, Wqkvt, QKVh, TT,
                                                                           QKVN, HIDDEN);
  normrope_kernel<<<(TT * (NH + NKV)) / 4, 256, 0, stream>>>(QKVh, q_norm_w, k_norm_w,
                                                             positions, Qh, Kh);
  gate_kernel<<<TT / 4, 256, 0, stream>>>(hidden, w_g, gate);
  attn_kernel<<<dim3(TT / 64, NH), 256, 0, stream>>>(Qh, Kh, QKVh, gate, positions, Og);
  gemm_bt_kernel<float><<<dim3(HIDDEN / 128, TT / 128), 256, 0, stream>>>(Og, Wot, out, TT,
                                                                          HIDDEN, QSIZE);
}

// Round 2
// 463.638 us; speedup vs baseline: 1.5608x; 1.5608x over previous
//
#include <hip/hip_runtime.h>

typedef __attribute__((ext_vector_type(4))) float floatx4;
typedef __attribute__((ext_vector_type(8))) _Float16 half8;
typedef __attribute__((ext_vector_type(4))) _Float16 half4;

#define TT 2048
#define HIDDEN 2048
#define NH 32
#define NKV 8
#define HD 128
#define QSIZE 4096
#define KVSIZE 1024
#define QKVN 6144
#define WINDOW 512

// ---------------- fp32 -> fp16 convert ----------------
__global__ __launch_bounds__(256) void cvt_f32_f16_kernel(const float* __restrict__ in,
                                                          _Float16* __restrict__ out) {
  int i = (blockIdx.x * 256 + threadIdx.x) * 4;
  float4 v = *(const float4*)&in[i];
  alignas(8) _Float16 o[4] = {(_Float16)v.x, (_Float16)v.y, (_Float16)v.z, (_Float16)v.w};
  *(uint2*)&out[i] = *(const uint2*)o;
}

// ---------------- fp32 [R][C] -> fp16 [C][R] transpose ----------------
__global__ __launch_bounds__(256) void transpose_f32_f16_kernel(
    const float* __restrict__ in, _Float16* __restrict__ out, int R, int C) {
  __shared__ float tile[32][33];
  int bc = blockIdx.x * 32;
  int br = blockIdx.y * 32;
  int c = threadIdx.x & 31;
  int r0 = threadIdx.x >> 5;  // 0..7
#pragma unroll
  for (int i = 0; i < 4; ++i) {
    int r = r0 + 8 * i;
    tile[r][c] = in[(size_t)(br + r) * C + bc + c];
  }
  __syncthreads();
#pragma unroll
  for (int i = 0; i < 4; ++i) {
    int r = r0 + 8 * i;
    out[(size_t)(bc + r) * R + br + c] = (_Float16)tile[c][r];
  }
}

// ---------------- fp16 V slice transpose: QKVh V-part [T][1024] -> Vt [1024][T] ----
__global__ __launch_bounds__(256) void transpose_v_kernel(const _Float16* __restrict__ QKVh,
                                                          _Float16* __restrict__ Vt) {
  __shared__ float tile[32][33];
  int tb = blockIdx.x * 32;  // t base
  int db = blockIdx.y * 32;  // d-global base (kv*128+d)
  int c = threadIdx.x & 31;
  int r0 = threadIdx.x >> 5;
#pragma unroll
  for (int i = 0; i < 4; ++i) {
    int r = r0 + 8 * i;
    tile[r][c] = (float)QKVh[(size_t)(tb + r) * QKVN + QSIZE + KVSIZE + db + c];
  }
  __syncthreads();
#pragma unroll
  for (int i = 0; i < 4; ++i) {
    int r = r0 + 8 * i;
    Vt[(size_t)(db + r) * TT + tb + c] = (_Float16)tile[c][r];
  }
}

// ---------------- async 16B global->LDS (wave-uniform LDS base + lane*16) -------
__device__ __forceinline__ void async16(const _Float16* g, _Float16* l) {
  __builtin_amdgcn_global_load_lds((const __attribute__((address_space(1))) void*)g,
                                   (__attribute__((address_space(3))) void*)l, 16, 0, 0);
}

// ---------------- MFMA GEMM: C[M][N] = A[M][K] * Bt[N][K]^T ----------------
// m97-style: global_load_lds width-16 staging. LDS layout half-index == 8*chunk.
template <typename OutT>
__global__ __launch_bounds__(256, 2) void gemm_bt_kernel(
    const _Float16* __restrict__ A, const _Float16* __restrict__ Bt,
    OutT* __restrict__ C, int M, int N, int K) {
  __shared__ _Float16 As[128 * 32];
  __shared__ _Float16 Bs[128 * 32];
  int tid = threadIdx.x;
  int wave = tid >> 6, lane = tid & 63;
  int wm = wave >> 1, wn = wave & 1;
  int m0 = blockIdx.y * 128, n0 = blockIdx.x * 128;
  int lr = lane & 15;
  int kq = (lane >> 4) * 8;
  floatx4 acc[4][4];
#pragma unroll
  for (int i = 0; i < 4; ++i)
#pragma unroll
    for (int j = 0; j < 4; ++j) acc[i][j] = (floatx4){0.f, 0.f, 0.f, 0.f};

  for (int k0 = 0; k0 < K; k0 += 32) {
    __syncthreads();  // all waves done reading previous tile
#pragma unroll
    for (int it = 0; it < 2; ++it) {
      int c = tid + it * 256;            // 512 chunks of 8 halfs per tile
      int row = c >> 2, kp = (c & 3) * 8;
      // lane's data lands at LDS halfs [8c .. 8c+7] == row*32+kp  (wave base + lane*16)
      _Float16* la = &As[it * 2048 + wave * 512];
      _Float16* lb = &Bs[it * 2048 + wave * 512];
      async16(&A[(size_t)(m0 + row) * K + k0 + kp], la);
      async16(&Bt[(size_t)(n0 + row) * K + k0 + kp], lb);
    }
    __syncthreads();  // waitcnt vmcnt(0) drains async loads
    half8 a[4], b[4];
#pragma unroll
    for (int i = 0; i < 4; ++i) a[i] = *(const half8*)&As[(wm * 64 + i * 16 + lr) * 32 + kq];
#pragma unroll
    for (int j = 0; j < 4; ++j) b[j] = *(const half8*)&Bs[(wn * 64 + j * 16 + lr) * 32 + kq];
#pragma unroll
    for (int i = 0; i < 4; ++i)
#pragma unroll
      for (int j = 0; j < 4; ++j)
        acc[i][j] = __builtin_amdgcn_mfma_f32_16x16x32_f16(a[i], b[j], acc[i][j], 0, 0, 0);
  }
  int rq = (lane >> 4) * 4;
#pragma unroll
  for (int i = 0; i < 4; ++i)
#pragma unroll
    for (int j = 0; j < 4; ++j)
#pragma unroll
      for (int r = 0; r < 4; ++r) {
        int row = m0 + wm * 64 + i * 16 + rq + r;
        int col = n0 + wn * 64 + j * 16 + lr;
        C[(size_t)row * N + col] = (OutT)acc[i][j][r];
      }
}

// ---------------- per-head RMSNorm + RoPE (wave per row) ----------------
__global__ __launch_bounds__(256) void normrope_kernel(
    const _Float16* __restrict__ qkv, const float* __restrict__ qw,
    const float* __restrict__ kw, const int* __restrict__ positions,
    _Float16* __restrict__ qh, _Float16* __restrict__ khb) {
  int wid = blockIdx.x * 4 + (threadIdx.x >> 6);
  int lane = threadIdx.x & 63;
  int t, hh;
  const _Float16* src;
  _Float16* dst;
  const float* w;
  if (wid < TT * NH) {
    t = wid >> 5; hh = wid & 31;
    src = qkv + (size_t)t * QKVN + hh * HD;
    dst = qh + ((size_t)t * NH + hh) * HD;
    w = qw;
  } else {
    int r = wid - TT * NH;
    t = r >> 3; hh = r & 7;
    src = qkv + (size_t)t * QKVN + QSIZE + hh * HD;
    dst = khb + ((size_t)t * NKV + hh) * HD;
    w = kw;
  }
  float x1 = (float)src[lane];
  float x2 = (float)src[lane + 64];
  float ss = x1 * x1 + x2 * x2;
#pragma unroll
  for (int off = 1; off < 64; off <<= 1) ss += __shfl_xor(ss, off);
  float rr = rsqrtf(ss * (1.0f / 128.0f) + 1e-6f);
  float n1 = x1 * rr * w[lane];
  float n2 = x2 * rr * w[lane + 64];
  float pos = (float)positions[t];
  float invf = exp2f(-(float)lane * (13.287712379549449f / 64.0f));  // 10000^(-lane/64)
  float ang = pos * invf;
  float sn, cs;
  sincosf(ang, &sn, &cs);
  dst[lane] = (_Float16)(n1 * cs - n2 * sn);
  dst[lane + 64] = (_Float16)(n2 * cs + n1 * sn);
}

// ---------------- gate = softplus(hidden @ w_g), 4 rows per block ----------------
__global__ __launch_bounds__(256) void gate_kernel(const float* __restrict__ hs,
                                                   const float* __restrict__ wg,
                                                   float* __restrict__ gate) {
  __shared__ float hrow[4][HIDDEN];
  __shared__ float red[4][8][32];
  int tid = threadIdx.x;
  int tb = blockIdx.x * 4;
  for (int c = tid; c < 4 * (HIDDEN / 4); c += 256) {
    int r = c >> 9, off = (c & 511) * 4;
    *(float4*)&hrow[r][off] = *(const float4*)&hs[(size_t)(tb + r) * HIDDEN + off];
  }
  __syncthreads();
  int hcol = tid & 31, part = tid >> 5;
  float p0 = 0.f, p1 = 0.f, p2 = 0.f, p3 = 0.f;
  for (int i = 0; i < 256; ++i) {
    int k = part * 256 + i;
    float w = wg[(size_t)k * NH + hcol];
    p0 += hrow[0][k] * w; p1 += hrow[1][k] * w;
    p2 += hrow[2][k] * w; p3 += hrow[3][k] * w;
  }
  red[0][part][hcol] = p0; red[1][part][hcol] = p1;
  red[2][part][hcol] = p2; red[3][part][hcol] = p3;
  __syncthreads();
  if (tid < 128) {
    int r = tid >> 5, hc = tid & 31;
    float s = 0.f;
#pragma unroll
    for (int p = 0; p < 8; ++p) s += red[r][p][hc];
    float sp = (s > 0.f) ? s + log1pf(expf(-s)) : log1pf(expf(s));
    gate[(size_t)(tb + r) * NH + hc] = sp;
  }
}

// ---------------- MFMA sliding-window attention, barrier-free ----------------
// block = (16 q-rows, kv-head); wave w handles q-head kh*4+w.
// K/V fragments loaded straight from global in B-layout (L1-shared across waves).
// Only LDS: per-wave 16x64 P tile for C-layout -> A-layout transform.
#define PSTR 68  // stride: quads land on disjoint bank groups for the scalar writes
__global__ __launch_bounds__(256) void attn_kernel(
    const _Float16* __restrict__ Qh, const _Float16* __restrict__ Kh,
    const _Float16* __restrict__ Vt, const float* __restrict__ gate,
    const int* __restrict__ positions, _Float16* __restrict__ Og) {
  const float scale = 0.08838834764831845f;  // 128^-0.5
  __shared__ _Float16 Ps[4][16 * PSTR];
  int tid = threadIdx.x;
  int wave = tid >> 6, lane = tid & 63;
  int n16 = lane & 15, quad = lane >> 4;
  int t0 = blockIdx.x * 16;
  int kh = blockIdx.y;
  int h = kh * 4 + wave;
  _Float16* ps = Ps[wave];

  // Q A-frags for all 9 key tiles: A[m=n16][k=kc*32+quad*8+j]
  half8 qf[4];
#pragma unroll
  for (int kc = 0; kc < 4; ++kc)
    qf[kc] = *(const half8*)&Qh[((size_t)(t0 + n16) * NH + h) * HD + kc * 32 + quad * 8];

  int pq[4];
#pragma unroll
  for (int r = 0; r < 4; ++r) pq[r] = positions[t0 + quad * 4 + r];

  floatx4 O[8];
#pragma unroll
  for (int jd = 0; jd < 8; ++jd) O[jd] = (floatx4){0.f, 0.f, 0.f, 0.f};
  float m_i[4] = {-1e30f, -1e30f, -1e30f, -1e30f};
  float l_i[4] = {0.f, 0.f, 0.f, 0.f};

  int lo = t0 - (WINDOW - 1);
  if (lo < 0) lo = 0;
  int st1 = (t0 + 15) >> 6;
  for (int st = lo >> 6; st <= st1; ++st) {
    int s0 = st * 64;
    // ---- QK^T: S C-frag rows=quad*4+r, col=jt*16+n16
    floatx4 S[4];
#pragma unroll
    for (int jt = 0; jt < 4; ++jt) {
      S[jt] = (floatx4){0.f, 0.f, 0.f, 0.f};
#pragma unroll
      for (int kc = 0; kc < 4; ++kc) {
        half8 kf = *(const half8*)&Kh[((size_t)(s0 + jt * 16 + n16) * NKV + kh) * HD +
                                      kc * 32 + quad * 8];
        S[jt] = __builtin_amdgcn_mfma_f32_16x16x32_f16(qf[kc], kf, S[jt], 0, 0, 0);
      }
    }
    int pk[4];
#pragma unroll
    for (int jt = 0; jt < 4; ++jt) pk[jt] = positions[s0 + jt * 16 + n16];
    // ---- mask + online softmax (row r owned by the 16 lanes of this quad)
#pragma unroll
    for (int r = 0; r < 4; ++r) {
      float v[4];
      float rmax = -1e30f;
#pragma unroll
      for (int jt = 0; jt < 4; ++jt) {
        int diff = pq[r] - pk[jt];
        bool ok = (diff >= 0) && (diff < WINDOW);
        v[jt] = ok ? S[jt][r] * scale : -1e30f;
        rmax = fmaxf(rmax, v[jt]);
      }
#pragma unroll
      for (int off = 1; off < 16; off <<= 1) rmax = fmaxf(rmax, __shfl_xor(rmax, off));
      float mnew = fmaxf(m_i[r], rmax);
      float alpha = __expf(m_i[r] - mnew);
      float psum = 0.f;
#pragma unroll
      for (int jt = 0; jt < 4; ++jt) {
        float pv = (v[jt] > -1e29f) ? __expf(v[jt] - mnew) : 0.f;
        v[jt] = pv;
        psum += pv;
      }
#pragma unroll
      for (int off = 1; off < 16; off <<= 1) psum += __shfl_xor(psum, off);
      m_i[r] = mnew;
      l_i[r] = l_i[r] * alpha + psum;
#pragma unroll
      for (int jd = 0; jd < 8; ++jd) O[jd][r] *= alpha;
#pragma unroll
      for (int jt = 0; jt < 4; ++jt)
        ps[(quad * 4 + r) * PSTR + jt * 16 + n16] = (_Float16)v[jt];
    }
    // ---- P: C-layout -> A-layout via wave-private LDS (in-order DS pipe, no barrier)
    half8 pf[2];
#pragma unroll
    for (int kc = 0; kc < 2; ++kc) {
      half4 lo4 = *(const half4*)&ps[n16 * PSTR + kc * 32 + quad * 8];
      half4 hi4 = *(const half4*)&ps[n16 * PSTR + kc * 32 + quad * 8 + 4];
      pf[kc] = (half8){lo4[0], lo4[1], lo4[2], lo4[3], hi4[0], hi4[1], hi4[2], hi4[3]};
    }
    // ---- PV: O rows=quad*4+r, col=jd*16+n16; V^T frags direct from Vt
#pragma unroll
    for (int jd = 0; jd < 8; ++jd) {
#pragma unroll
      for (int kc = 0; kc < 2; ++kc) {
        half8 vf = *(const half8*)&Vt[(size_t)(kh * HD + jd * 16 + n16) * TT + s0 +
                                      kc * 32 + quad * 8];
        O[jd] = __builtin_amdgcn_mfma_f32_16x16x32_f16(pf[kc], vf, O[jd], 0, 0, 0);
      }
    }
  }
  // ---- epilogue: normalize, gate, store
#pragma unroll
  for (int r = 0; r < 4; ++r) {
    int t = t0 + quad * 4 + r;
    float g = gate[(size_t)t * NH + h];
    float inv = g / l_i[r];
#pragma unroll
    for (int jd = 0; jd < 8; ++jd)
      Og[(size_t)t * QSIZE + h * HD + jd * 16 + n16] = (_Float16)(O[jd][r] * inv);
  }
}

// ---------------- launcher ----------------
extern "C" void kernel_launch(void* const* d_in, const int* in_sizes, int n_in,
                              void* d_out, int out_size, void* d_ws, size_t ws_size,
                              hipStream_t stream) {
  const int* positions = (const int*)d_in[0];
  const float* hidden = (const float*)d_in[1];
  const float* w_qkv = (const float*)d_in[2];
  const float* w_o = (const float*)d_in[3];
  const float* w_g = (const float*)d_in[4];
  const float* q_norm_w = (const float*)d_in[5];
  const float* k_norm_w = (const float*)d_in[6];
  float* out = (float*)d_out;

  char* ws = (char*)d_ws;
  size_t off = 0;
  auto alloc = [&](size_t bytes) {
    void* p = ws + off;
    off += (bytes + 255) & ~(size_t)255;
    return p;
  };
  _Float16* Xb = (_Float16*)alloc((size_t)TT * HIDDEN * 2);
  _Float16* Wqkvt = (_Float16*)alloc((size_t)QKVN * HIDDEN * 2);
  _Float16* Wot = (_Float16*)alloc((size_t)HIDDEN * QSIZE * 2);
  _Float16* QKVh = (_Float16*)alloc((size_t)TT * QKVN * 2);
  _Float16* Qh = (_Float16*)alloc((size_t)TT * NH * HD * 2);
  _Float16* Kh = (_Float16*)alloc((size_t)TT * NKV * HD * 2);
  _Float16* Vt = (_Float16*)alloc((size_t)KVSIZE * TT * 2);
  float* gate = (float*)alloc((size_t)TT * NH * 4);
  _Float16* Og = (_Float16*)alloc((size_t)TT * QSIZE * 2);

  cvt_f32_f16_kernel<<<(TT * HIDDEN) / 1024, 256, 0, stream>>>(hidden, Xb);
  transpose_f32_f16_kernel<<<dim3(QKVN / 32, HIDDEN / 32), 256, 0, stream>>>(w_qkv, Wqkvt,
                                                                             HIDDEN, QKVN);
  transpose_f32_f16_kernel<<<dim3(HIDDEN / 32, QSIZE / 32), 256, 0, stream>>>(w_o, Wot, QSIZE,
                                                                              HIDDEN);
  gemm_bt_kernel<_Float16><<<dim3(QKVN / 128, TT / 128), 256, 0, stream>>>(Xb, Wqkvt, QKVh, TT,
                                                                           QKVN, HIDDEN);
  normrope_kernel<<<(TT * (NH + NKV)) / 4, 256, 0, stream>>>(QKVh, q_norm_w, k_norm_w,
                                                             positions, Qh, Kh);
  transpose_v_kernel<<<dim3(TT / 32, KVSIZE / 32), 256, 0, stream>>>(QKVh, Vt);
  gate_kernel<<<TT / 4, 256, 0, stream>>>(hidden, w_g, gate);
  attn_kernel<<<dim3(TT / 16, NKV), 256, 0, stream>>>(Qh, Kh, Vt, gate, positions, Og);
  gemm_bt_kernel<float><<<dim3(HIDDEN / 128, TT / 128), 256, 0, stream>>>(Og, Wot, out, TT,
                                                                          HIDDEN, QSIZE);
}

// Round 3
// 399.572 us; speedup vs baseline: 1.8110x; 1.1603x over previous
//
#include <hip/hip_runtime.h>

typedef __attribute__((ext_vector_type(4))) float floatx4;
typedef __attribute__((ext_vector_type(8))) _Float16 half8;
typedef __attribute__((ext_vector_type(4))) _Float16 half4;

#define TT 2048
#define HIDDEN 2048
#define NH 32
#define NKV 8
#define HD 128
#define QSIZE 4096
#define KVSIZE 1024
#define QKVN 6144
#define WINDOW 512

// ---------------- fp32 -> fp16 convert ----------------
__global__ __launch_bounds__(256) void cvt_f32_f16_kernel(const float* __restrict__ in,
                                                          _Float16* __restrict__ out) {
  int i = (blockIdx.x * 256 + threadIdx.x) * 4;
  float4 v = *(const float4*)&in[i];
  alignas(8) _Float16 o[4] = {(_Float16)v.x, (_Float16)v.y, (_Float16)v.z, (_Float16)v.w};
  *(uint2*)&out[i] = *(const uint2*)o;
}

// ---------------- fp32 [R][C] -> fp16 [C][R] transpose ----------------
__global__ __launch_bounds__(256) void transpose_f32_f16_kernel(
    const float* __restrict__ in, _Float16* __restrict__ out, int R, int C) {
  __shared__ float tile[32][33];
  int bc = blockIdx.x * 32;
  int br = blockIdx.y * 32;
  int c = threadIdx.x & 31;
  int r0 = threadIdx.x >> 5;  // 0..7
#pragma unroll
  for (int i = 0; i < 4; ++i) {
    int r = r0 + 8 * i;
    tile[r][c] = in[(size_t)(br + r) * C + bc + c];
  }
  __syncthreads();
#pragma unroll
  for (int i = 0; i < 4; ++i) {
    int r = r0 + 8 * i;
    out[(size_t)(bc + r) * R + br + c] = (_Float16)tile[c][r];
  }
}

// ---------------- fp16 V slice transpose: QKVh V-part [T][1024] -> Vt [1024][T] ----
__global__ __launch_bounds__(256) void transpose_v_kernel(const _Float16* __restrict__ QKVh,
                                                          _Float16* __restrict__ Vt) {
  __shared__ float tile[32][33];
  int tb = blockIdx.x * 32;  // t base
  int db = blockIdx.y * 32;  // d-global base (kv*128+d)
  int c = threadIdx.x & 31;
  int r0 = threadIdx.x >> 5;
#pragma unroll
  for (int i = 0; i < 4; ++i) {
    int r = r0 + 8 * i;
    tile[r][c] = (float)QKVh[(size_t)(tb + r) * QKVN + QSIZE + KVSIZE + db + c];
  }
  __syncthreads();
#pragma unroll
  for (int i = 0; i < 4; ++i) {
    int r = r0 + 8 * i;
    Vt[(size_t)(db + r) * TT + tb + c] = (_Float16)tile[c][r];
  }
}

// ---------------- K -> fragment-linear repack --------------------------------
// Kf[kh][st][jt][kc][quad][n16][8]: attention B-frag load becomes base+lane*16B.
__global__ __launch_bounds__(256) void repack_k_kernel(const _Float16* __restrict__ Kh,
                                                       _Float16* __restrict__ Kf) {
  int st = blockIdx.x, kh = blockIdx.y;
  int s0 = st * 64;
  _Float16* dst = Kf + (size_t)(kh * 32 + st) * 8192;
#pragma unroll
  for (int i = 0; i < 4; ++i) {
    int c = threadIdx.x + i * 256;  // c = jt*256 + kc*64 + quad*16 + n16
    int jt = c >> 8, kc = (c >> 6) & 3, quad = (c >> 4) & 3, n16 = c & 15;
    uint4 v = *(const uint4*)&Kh[((size_t)(s0 + jt * 16 + n16) * NKV + kh) * HD +
                                 kc * 32 + quad * 8];
    *(uint4*)&dst[c * 8] = v;
  }
}

// ---------------- V^T -> fragment-linear repack ------------------------------
// Vf[kh][st][jd][kc][quad][n16][8]
__global__ __launch_bounds__(256) void repack_v_kernel(const _Float16* __restrict__ Vt,
                                                       _Float16* __restrict__ Vf) {
  int st = blockIdx.x, kh = blockIdx.y;
  int s0 = st * 64;
  _Float16* dst = Vf + (size_t)(kh * 32 + st) * 8192;
#pragma unroll
  for (int i = 0; i < 4; ++i) {
    int c = threadIdx.x + i * 256;  // c = jd*128 + kc*64 + quad*16 + n16
    int jd = c >> 7, kc = (c >> 6) & 1, quad = (c >> 4) & 3, n16 = c & 15;
    uint4 v = *(const uint4*)&Vt[(size_t)(kh * HD + jd * 16 + n16) * TT + s0 +
                                 kc * 32 + quad * 8];
    *(uint4*)&dst[c * 8] = v;
  }
}

// ---------------- async 16B global->LDS (wave-uniform LDS base + lane*16) -------
__device__ __forceinline__ void async16(const _Float16* g, _Float16* l) {
  __builtin_amdgcn_global_load_lds((const __attribute__((address_space(1))) void*)g,
                                   (__attribute__((address_space(3))) void*)l, 16, 0, 0);
}

// ---------------- MFMA GEMM: C[M][N] = A[M][K] * Bt[N][K]^T ----------------
template <typename OutT>
__global__ __launch_bounds__(256, 2) void gemm_bt_kernel(
    const _Float16* __restrict__ A, const _Float16* __restrict__ Bt,
    OutT* __restrict__ C, int M, int N, int K) {
  __shared__ _Float16 As[128 * 32];
  __shared__ _Float16 Bs[128 * 32];
  int tid = threadIdx.x;
  int wave = tid >> 6, lane = tid & 63;
  int wm = wave >> 1, wn = wave & 1;
  int m0 = blockIdx.y * 128, n0 = blockIdx.x * 128;
  int lr = lane & 15;
  int kq = (lane >> 4) * 8;
  floatx4 acc[4][4];
#pragma unroll
  for (int i = 0; i < 4; ++i)
#pragma unroll
    for (int j = 0; j < 4; ++j) acc[i][j] = (floatx4){0.f, 0.f, 0.f, 0.f};

  for (int k0 = 0; k0 < K; k0 += 32) {
    __syncthreads();
#pragma unroll
    for (int it = 0; it < 2; ++it) {
      int c = tid + it * 256;
      int row = c >> 2, kp = (c & 3) * 8;
      _Float16* la = &As[it * 2048 + wave * 512];
      _Float16* lb = &Bs[it * 2048 + wave * 512];
      async16(&A[(size_t)(m0 + row) * K + k0 + kp], la);
      async16(&Bt[(size_t)(n0 + row) * K + k0 + kp], lb);
    }
    __syncthreads();
    half8 a[4], b[4];
#pragma unroll
    for (int i = 0; i < 4; ++i) a[i] = *(const half8*)&As[(wm * 64 + i * 16 + lr) * 32 + kq];
#pragma unroll
    for (int j = 0; j < 4; ++j) b[j] = *(const half8*)&Bs[(wn * 64 + j * 16 + lr) * 32 + kq];
#pragma unroll
    for (int i = 0; i < 4; ++i)
#pragma unroll
      for (int j = 0; j < 4; ++j)
        acc[i][j] = __builtin_amdgcn_mfma_f32_16x16x32_f16(a[i], b[j], acc[i][j], 0, 0, 0);
  }
  int rq = (lane >> 4) * 4;
#pragma unroll
  for (int i = 0; i < 4; ++i)
#pragma unroll
    for (int j = 0; j < 4; ++j)
#pragma unroll
      for (int r = 0; r < 4; ++r) {
        int row = m0 + wm * 64 + i * 16 + rq + r;
        int col = n0 + wn * 64 + j * 16 + lr;
        C[(size_t)row * N + col] = (OutT)acc[i][j][r];
      }
}

// ---------------- per-head RMSNorm + RoPE (wave per row) ----------------
__global__ __launch_bounds__(256) void normrope_kernel(
    const _Float16* __restrict__ qkv, const float* __restrict__ qw,
    const float* __restrict__ kw, const int* __restrict__ positions,
    _Float16* __restrict__ qh, _Float16* __restrict__ khb) {
  int wid = blockIdx.x * 4 + (threadIdx.x >> 6);
  int lane = threadIdx.x & 63;
  int t, hh;
  const _Float16* src;
  _Float16* dst;
  const float* w;
  if (wid < TT * NH) {
    t = wid >> 5; hh = wid & 31;
    src = qkv + (size_t)t * QKVN + hh * HD;
    dst = qh + ((size_t)t * NH + hh) * HD;
    w = qw;
  } else {
    int r = wid - TT * NH;
    t = r >> 3; hh = r & 7;
    src = qkv + (size_t)t * QKVN + QSIZE + hh * HD;
    dst = khb + ((size_t)t * NKV + hh) * HD;
    w = kw;
  }
  float x1 = (float)src[lane];
  float x2 = (float)src[lane + 64];
  float ss = x1 * x1 + x2 * x2;
#pragma unroll
  for (int off = 1; off < 64; off <<= 1) ss += __shfl_xor(ss, off);
  float rr = rsqrtf(ss * (1.0f / 128.0f) + 1e-6f);
  float n1 = x1 * rr * w[lane];
  float n2 = x2 * rr * w[lane + 64];
  float pos = (float)positions[t];
  float invf = exp2f(-(float)lane * (13.287712379549449f / 64.0f));  // 10000^(-lane/64)
  float ang = pos * invf;
  float sn, cs;
  sincosf(ang, &sn, &cs);
  dst[lane] = (_Float16)(n1 * cs - n2 * sn);
  dst[lane + 64] = (_Float16)(n2 * cs + n1 * sn);
}

// ---------------- gate = softplus(hidden @ w_g), 4 rows per block ----------------
__global__ __launch_bounds__(256) void gate_kernel(const float* __restrict__ hs,
                                                   const float* __restrict__ wg,
                                                   float* __restrict__ gate) {
  __shared__ float hrow[4][HIDDEN];
  __shared__ float red[4][8][32];
  int tid = threadIdx.x;
  int tb = blockIdx.x * 4;
  for (int c = tid; c < 4 * (HIDDEN / 4); c += 256) {
    int r = c >> 9, off = (c & 511) * 4;
    *(float4*)&hrow[r][off] = *(const float4*)&hs[(size_t)(tb + r) * HIDDEN + off];
  }
  __syncthreads();
  int hcol = tid & 31, part = tid >> 5;
  float p0 = 0.f, p1 = 0.f, p2 = 0.f, p3 = 0.f;
  for (int i = 0; i < 256; ++i) {
    int k = part * 256 + i;
    float w = wg[(size_t)k * NH + hcol];
    p0 += hrow[0][k] * w; p1 += hrow[1][k] * w;
    p2 += hrow[2][k] * w; p3 += hrow[3][k] * w;
  }
  red[0][part][hcol] = p0; red[1][part][hcol] = p1;
  red[2][part][hcol] = p2; red[3][part][hcol] = p3;
  __syncthreads();
  if (tid < 128) {
    int r = tid >> 5, hc = tid & 31;
    float s = 0.f;
#pragma unroll
    for (int p = 0; p < 8; ++p) s += red[r][p][hc];
    float sp = (s > 0.f) ? s + log1pf(expf(-s)) : log1pf(expf(s));
    gate[(size_t)(tb + r) * NH + hc] = sp;
  }
}

// ---------------- MFMA sliding-window attention, barrier-free ----------------
// block = (32 q-rows, kv-head); wave w = q-head kh*4+w, handles 2 m-tiles of 16.
// All K/V fragment loads are contiguous 1KB wave transactions from Kf/Vf.
#define PSTR 68
__global__ __launch_bounds__(256, 2) void attn_kernel(
    const _Float16* __restrict__ Qh, const _Float16* __restrict__ Kf,
    const _Float16* __restrict__ Vf, const float* __restrict__ gate,
    const int* __restrict__ positions, _Float16* __restrict__ Og) {
  const float scale = 0.08838834764831845f;  // 128^-0.5
  __shared__ _Float16 Ps[4][2 * 16 * PSTR];
  int tid = threadIdx.x;
  int wave = tid >> 6, lane = tid & 63;
  int n16 = lane & 15, quad = lane >> 4;
  int t0 = blockIdx.x * 32;
  int kh = blockIdx.y;
  int h = kh * 4 + wave;
  _Float16* ps = Ps[wave];

  // Q A-frags: A[m=n16][k=kc*32+quad*8+j], two m-tiles
  half8 qf[2][4];
#pragma unroll
  for (int mt = 0; mt < 2; ++mt)
#pragma unroll
    for (int kc = 0; kc < 4; ++kc)
      qf[mt][kc] = *(const half8*)&Qh[((size_t)(t0 + mt * 16 + n16) * NH + h) * HD +
                                      kc * 32 + quad * 8];
  int pq[2][4];
#pragma unroll
  for (int mt = 0; mt < 2; ++mt)
#pragma unroll
    for (int r = 0; r < 4; ++r) pq[mt][r] = positions[t0 + mt * 16 + quad * 4 + r];

  floatx4 O[2][8];
  float m_i[2][4], l_i[2][4];
#pragma unroll
  for (int mt = 0; mt < 2; ++mt) {
#pragma unroll
    for (int jd = 0; jd < 8; ++jd) O[mt][jd] = (floatx4){0.f, 0.f, 0.f, 0.f};
#pragma unroll
    for (int r = 0; r < 4; ++r) { m_i[mt][r] = -1e30f; l_i[mt][r] = 0.f; }
  }

  int lo = t0 - (WINDOW - 1);
  if (lo < 0) lo = 0;
  int st1 = (t0 + 31) >> 6;
  for (int st = lo >> 6; st <= st1; ++st) {
    int s0 = st * 64;
    const _Float16* kb = Kf + (size_t)(kh * 32 + st) * 8192;
    const _Float16* vb = Vf + (size_t)(kh * 32 + st) * 8192;
    // ---- QK^T: 16 contiguous K loads, 32 MFMA (2 indep m-chains)
    floatx4 S[2][4];
#pragma unroll
    for (int mt = 0; mt < 2; ++mt)
#pragma unroll
      for (int jt = 0; jt < 4; ++jt) S[mt][jt] = (floatx4){0.f, 0.f, 0.f, 0.f};
#pragma unroll
    for (int jt = 0; jt < 4; ++jt) {
      half8 kf[4];
#pragma unroll
      for (int kc = 0; kc < 4; ++kc)
        kf[kc] = *(const half8*)&kb[(jt * 4 + kc) * 512 + lane * 8];
#pragma unroll
      for (int kc = 0; kc < 4; ++kc)
#pragma unroll
        for (int mt = 0; mt < 2; ++mt)
          S[mt][jt] = __builtin_amdgcn_mfma_f32_16x16x32_f16(qf[mt][kc], kf[kc], S[mt][jt], 0, 0, 0);
    }
    int pk[4];
#pragma unroll
    for (int jt = 0; jt < 4; ++jt) pk[jt] = positions[s0 + jt * 16 + n16];
    // ---- mask + online softmax
#pragma unroll
    for (int mt = 0; mt < 2; ++mt)
#pragma unroll
      for (int r = 0; r < 4; ++r) {
        float v[4];
        float rmax = -1e30f;
#pragma unroll
        for (int jt = 0; jt < 4; ++jt) {
          int diff = pq[mt][r] - pk[jt];
          bool ok = (diff >= 0) && (diff < WINDOW);
          v[jt] = ok ? S[mt][jt][r] * scale : -1e30f;
          rmax = fmaxf(rmax, v[jt]);
        }
#pragma unroll
        for (int off = 1; off < 16; off <<= 1) rmax = fmaxf(rmax, __shfl_xor(rmax, off));
        float mnew = fmaxf(m_i[mt][r], rmax);
        float alpha = __expf(m_i[mt][r] - mnew);
        float psum = 0.f;
#pragma unroll
        for (int jt = 0; jt < 4; ++jt) {
          float pv = (v[jt] > -1e29f) ? __expf(v[jt] - mnew) : 0.f;
          v[jt] = pv;
          psum += pv;
        }
#pragma unroll
        for (int off = 1; off < 16; off <<= 1) psum += __shfl_xor(psum, off);
        m_i[mt][r] = mnew;
        l_i[mt][r] = l_i[mt][r] * alpha + psum;
#pragma unroll
        for (int jd = 0; jd < 8; ++jd) O[mt][jd][r] *= alpha;
#pragma unroll
        for (int jt = 0; jt < 4; ++jt)
          ps[(mt * 16 + quad * 4 + r) * PSTR + jt * 16 + n16] = (_Float16)v[jt];
      }
    // ---- P: C-layout -> A-layout via wave-private LDS (in-order DS pipe, no barrier)
    half8 pf[2][2];
#pragma unroll
    for (int mt = 0; mt < 2; ++mt)
#pragma unroll
      for (int kc = 0; kc < 2; ++kc) {
        half4 lo4 = *(const half4*)&ps[(mt * 16 + n16) * PSTR + kc * 32 + quad * 8];
        half4 hi4 = *(const half4*)&ps[(mt * 16 + n16) * PSTR + kc * 32 + quad * 8 + 4];
        pf[mt][kc] = (half8){lo4[0], lo4[1], lo4[2], lo4[3], hi4[0], hi4[1], hi4[2], hi4[3]};
      }
    // ---- PV: 16 contiguous V loads, 32 MFMA
#pragma unroll
    for (int jd = 0; jd < 8; ++jd) {
#pragma unroll
      for (int kc = 0; kc < 2; ++kc) {
        half8 vf = *(const half8*)&vb[(jd * 2 + kc) * 512 + lane * 8];
#pragma unroll
        for (int mt = 0; mt < 2; ++mt)
          O[mt][jd] = __builtin_amdgcn_mfma_f32_16x16x32_f16(pf[mt][kc], vf, O[mt][jd], 0, 0, 0);
      }
    }
  }
  // ---- epilogue: normalize, gate, store
#pragma unroll
  for (int mt = 0; mt < 2; ++mt)
#pragma unroll
    for (int r = 0; r < 4; ++r) {
      int t = t0 + mt * 16 + quad * 4 + r;
      float g = gate[(size_t)t * NH + h];
      float inv = g / l_i[mt][r];
#pragma unroll
      for (int jd = 0; jd < 8; ++jd)
        Og[(size_t)t * QSIZE + h * HD + jd * 16 + n16] = (_Float16)(O[mt][jd][r] * inv);
    }
}

// ---------------- launcher ----------------
extern "C" void kernel_launch(void* const* d_in, const int* in_sizes, int n_in,
                              void* d_out, int out_size, void* d_ws, size_t ws_size,
                              hipStream_t stream) {
  const int* positions = (const int*)d_in[0];
  const float* hidden = (const float*)d_in[1];
  const float* w_qkv = (const float*)d_in[2];
  const float* w_o = (const float*)d_in[3];
  const float* w_g = (const float*)d_in[4];
  const float* q_norm_w = (const float*)d_in[5];
  const float* k_norm_w = (const float*)d_in[6];
  float* out = (float*)d_out;

  char* ws = (char*)d_ws;
  size_t off = 0;
  auto alloc = [&](size_t bytes) {
    void* p = ws + off;
    off += (bytes + 255) & ~(size_t)255;
    return p;
  };
  _Float16* Xb = (_Float16*)alloc((size_t)TT * HIDDEN * 2);
  _Float16* Wqkvt = (_Float16*)alloc((size_t)QKVN * HIDDEN * 2);
  _Float16* Wot = (_Float16*)alloc((size_t)HIDDEN * QSIZE * 2);
  _Float16* QKVh = (_Float16*)alloc((size_t)TT * QKVN * 2);
  _Float16* Qh = (_Float16*)alloc((size_t)TT * NH * HD * 2);
  _Float16* Kh = (_Float16*)alloc((size_t)TT * NKV * HD * 2);
  _Float16* Vt = (_Float16*)alloc((size_t)KVSIZE * TT * 2);
  _Float16* Kf = (_Float16*)alloc((size_t)NKV * 32 * 8192 * 2);
  _Float16* Vf = (_Float16*)alloc((size_t)NKV * 32 * 8192 * 2);
  float* gate = (float*)alloc((size_t)TT * NH * 4);
  _Float16* Og = (_Float16*)alloc((size_t)TT * QSIZE * 2);

  cvt_f32_f16_kernel<<<(TT * HIDDEN) / 1024, 256, 0, stream>>>(hidden, Xb);
  transpose_f32_f16_kernel<<<dim3(QKVN / 32, HIDDEN / 32), 256, 0, stream>>>(w_qkv, Wqkvt,
                                                                             HIDDEN, QKVN);
  transpose_f32_f16_kernel<<<dim3(HIDDEN / 32, QSIZE / 32), 256, 0, stream>>>(w_o, Wot, QSIZE,
                                                                              HIDDEN);
  gemm_bt_kernel<_Float16><<<dim3(QKVN / 128, TT / 128), 256, 0, stream>>>(Xb, Wqkvt, QKVh, TT,
                                                                           QKVN, HIDDEN);
  normrope_kernel<<<(TT * (NH + NKV)) / 4, 256, 0, stream>>>(QKVh, q_norm_w, k_norm_w,
                                                             positions, Qh, Kh);
  transpose_v_kernel<<<dim3(TT / 32, KVSIZE / 32), 256, 0, stream>>>(QKVh, Vt);
  repack_k_kernel<<<dim3(32, NKV), 256, 0, stream>>>(Kh, Kf);
  repack_v_kernel<<<dim3(32, NKV), 256, 0, stream>>>(Vt, Vf);
  gate_kernel<<<TT / 4, 256, 0, stream>>>(hidden, w_g, gate);
  attn_kernel<<<dim3(TT / 32, NKV), 256, 0, stream>>>(Qh, Kf, Vf, gate, positions, Og);
  gemm_bt_kernel<float><<<dim3(HIDDEN / 128, TT / 128), 256, 0, stream>>>(Og, Wot, out, TT,
                                                                          HIDDEN, QSIZE);
}

// Round 4
// 380.110 us; speedup vs baseline: 1.9038x; 1.0512x over previous
//
#include <hip/hip_runtime.h>

typedef __attribute__((ext_vector_type(4))) float floatx4;
typedef __attribute__((ext_vector_type(8))) _Float16 half8;
typedef __attribute__((ext_vector_type(4))) _Float16 half4;

#define TT 2048
#define HIDDEN 2048
#define NH 32
#define NKV 8
#define HD 128
#define QSIZE 4096
#define KVSIZE 1024
#define QKVN 6144
#define QKVNP 6272   // padded: +32 gate cols +96 zero
#define VOFF 5120
#define GOFF 6144
#define WINDOW 512

// ---------------- fp32 -> fp16 convert ----------------
__global__ __launch_bounds__(256) void cvt_f32_f16_kernel(const float* __restrict__ in,
                                                          _Float16* __restrict__ out) {
  int i = (blockIdx.x * 256 + threadIdx.x) * 4;
  float4 v = *(const float4*)&in[i];
  alignas(8) _Float16 o[4] = {(_Float16)v.x, (_Float16)v.y, (_Float16)v.z, (_Float16)v.w};
  *(uint2*)&out[i] = *(const uint2*)o;
}

// ---------------- fp32 [R][C] -> fp16 [C][R] transpose ----------------
__global__ __launch_bounds__(256) void transpose_f32_f16_kernel(
    const float* __restrict__ in, _Float16* __restrict__ out, int R, int C) {
  __shared__ float tile[32][33];
  int bc = blockIdx.x * 32;
  int br = blockIdx.y * 32;
  int c = threadIdx.x & 31;
  int r0 = threadIdx.x >> 5;  // 0..7
#pragma unroll
  for (int i = 0; i < 4; ++i) {
    int r = r0 + 8 * i;
    tile[r][c] = in[(size_t)(br + r) * C + bc + c];
  }
  __syncthreads();
#pragma unroll
  for (int i = 0; i < 4; ++i) {
    int r = r0 + 8 * i;
    out[(size_t)(bc + r) * R + br + c] = (_Float16)tile[c][r];
  }
}

// ---------------- K -> fragment-linear repack --------------------------------
// Kf[kh][st][jt][kc][quad][n16][8]: attention B-frag load becomes base+lane*16B.
__global__ __launch_bounds__(256) void repack_k_kernel(const _Float16* __restrict__ Kh,
                                                       _Float16* __restrict__ Kf) {
  int st = blockIdx.x, kh = blockIdx.y;
  int s0 = st * 64;
  _Float16* dst = Kf + (size_t)(kh * 32 + st) * 8192;
#pragma unroll
  for (int i = 0; i < 4; ++i) {
    int c = threadIdx.x + i * 256;  // c = jt*256 + kc*64 + quad*16 + n16
    int jt = c >> 8, kc = (c >> 6) & 3, quad = (c >> 4) & 3, n16 = c & 15;
    uint4 v = *(const uint4*)&Kh[((size_t)(s0 + jt * 16 + n16) * NKV + kh) * HD +
                                 kc * 32 + quad * 8];
    *(uint4*)&dst[c * 8] = v;
  }
}

// ---------------- V -> fragment-linear repack, straight from QKVh ------------
// Vf[kh][st][jd][kc][quad][n16][8]; frag element (lane,j): d=jd*16+n16, s=kc*32+quad*8+j
__global__ __launch_bounds__(256) void repack_v_kernel(const _Float16* __restrict__ QKVh,
                                                       _Float16* __restrict__ Vf) {
  __shared__ _Float16 tile[64][136];  // [s][d], pad 8 halfs
  int st = blockIdx.x, kh = blockIdx.y;
  int s0 = st * 64;
#pragma unroll
  for (int i = 0; i < 4; ++i) {
    int c = threadIdx.x + i * 256;  // c = row*16 + part
    int row = c >> 4, part = c & 15;
    *(uint4*)&tile[row][part * 8] =
        *(const uint4*)&QKVh[(size_t)(s0 + row) * QKVNP + VOFF + kh * HD + part * 8];
  }
  __syncthreads();
  _Float16* dst = Vf + (size_t)(kh * 32 + st) * 8192;
#pragma unroll
  for (int i = 0; i < 4; ++i) {
    int c = threadIdx.x + i * 256;  // c = jd*128 + kc*64 + quad*16 + n16
    int jd = c >> 7, kc = (c >> 6) & 1, quad = (c >> 4) & 3, n16 = c & 15;
    int d = jd * 16 + n16, sb = kc * 32 + quad * 8;
    alignas(16) _Float16 tmp[8];
#pragma unroll
    for (int j = 0; j < 8; ++j) tmp[j] = tile[sb + j][d];
    *(uint4*)&dst[c * 8] = *(const uint4*)tmp;
  }
}

// ---------------- async 16B global->LDS (wave-uniform LDS base + lane*16) -------
__device__ __forceinline__ void async16(const _Float16* g, _Float16* l) {
  __builtin_amdgcn_global_load_lds((const __attribute__((address_space(1))) void*)g,
                                   (__attribute__((address_space(3))) void*)l, 16, 0, 0);
}

// ---------------- MFMA GEMM: C[M][N] = A[M][K] * Bt[N][K]^T ----------------
template <typename OutT>
__global__ __launch_bounds__(256, 2) void gemm_bt_kernel(
    const _Float16* __restrict__ A, const _Float16* __restrict__ Bt,
    OutT* __restrict__ C, int M, int N, int K) {
  __shared__ _Float16 As[128 * 32];
  __shared__ _Float16 Bs[128 * 32];
  int tid = threadIdx.x;
  int wave = tid >> 6, lane = tid & 63;
  int wm = wave >> 1, wn = wave & 1;
  int m0 = blockIdx.y * 128, n0 = blockIdx.x * 128;
  int lr = lane & 15;
  int kq = (lane >> 4) * 8;
  floatx4 acc[4][4];
#pragma unroll
  for (int i = 0; i < 4; ++i)
#pragma unroll
    for (int j = 0; j < 4; ++j) acc[i][j] = (floatx4){0.f, 0.f, 0.f, 0.f};

  for (int k0 = 0; k0 < K; k0 += 32) {
    __syncthreads();
#pragma unroll
    for (int it = 0; it < 2; ++it) {
      int c = tid + it * 256;
      int row = c >> 2, kp = (c & 3) * 8;
      _Float16* la = &As[it * 2048 + wave * 512];
      _Float16* lb = &Bs[it * 2048 + wave * 512];
      async16(&A[(size_t)(m0 + row) * K + k0 + kp], la);
      async16(&Bt[(size_t)(n0 + row) * K + k0 + kp], lb);
    }
    __syncthreads();
    half8 a[4], b[4];
#pragma unroll
    for (int i = 0; i < 4; ++i) a[i] = *(const half8*)&As[(wm * 64 + i * 16 + lr) * 32 + kq];
#pragma unroll
    for (int j = 0; j < 4; ++j) b[j] = *(const half8*)&Bs[(wn * 64 + j * 16 + lr) * 32 + kq];
#pragma unroll
    for (int i = 0; i < 4; ++i)
#pragma unroll
      for (int j = 0; j < 4; ++j)
        acc[i][j] = __builtin_amdgcn_mfma_f32_16x16x32_f16(a[i], b[j], acc[i][j], 0, 0, 0);
  }
  int rq = (lane >> 4) * 4;
#pragma unroll
  for (int i = 0; i < 4; ++i)
#pragma unroll
    for (int j = 0; j < 4; ++j)
#pragma unroll
      for (int r = 0; r < 4; ++r) {
        int row = m0 + wm * 64 + i * 16 + rq + r;
        int col = n0 + wn * 64 + j * 16 + lr;
        C[(size_t)row * N + col] = (OutT)acc[i][j][r];
      }
}

// ---------------- split-K MFMA GEMM, fp32 atomic epilogue --------------------
// grid.z picks a K-slice of length Ks; C must be zeroed before launch.
__global__ __launch_bounds__(256, 2) void gemm_bt_splitk_kernel(
    const _Float16* __restrict__ A, const _Float16* __restrict__ Bt,
    float* __restrict__ C, int M, int N, int K, int Ks) {
  __shared__ _Float16 As[128 * 32];
  __shared__ _Float16 Bs[128 * 32];
  int tid = threadIdx.x;
  int wave = tid >> 6, lane = tid & 63;
  int wm = wave >> 1, wn = wave & 1;
  int m0 = blockIdx.y * 128, n0 = blockIdx.x * 128;
  int kb = blockIdx.z * Ks;
  int lr = lane & 15;
  int kq = (lane >> 4) * 8;
  floatx4 acc[4][4];
#pragma unroll
  for (int i = 0; i < 4; ++i)
#pragma unroll
    for (int j = 0; j < 4; ++j) acc[i][j] = (floatx4){0.f, 0.f, 0.f, 0.f};

  for (int k0 = kb; k0 < kb + Ks; k0 += 32) {
    __syncthreads();
#pragma unroll
    for (int it = 0; it < 2; ++it) {
      int c = tid + it * 256;
      int row = c >> 2, kp = (c & 3) * 8;
      _Float16* la = &As[it * 2048 + wave * 512];
      _Float16* lb = &Bs[it * 2048 + wave * 512];
      async16(&A[(size_t)(m0 + row) * K + k0 + kp], la);
      async16(&Bt[(size_t)(n0 + row) * K + k0 + kp], lb);
    }
    __syncthreads();
    half8 a[4], b[4];
#pragma unroll
    for (int i = 0; i < 4; ++i) a[i] = *(const half8*)&As[(wm * 64 + i * 16 + lr) * 32 + kq];
#pragma unroll
    for (int j = 0; j < 4; ++j) b[j] = *(const half8*)&Bs[(wn * 64 + j * 16 + lr) * 32 + kq];
#pragma unroll
    for (int i = 0; i < 4; ++i)
#pragma unroll
      for (int j = 0; j < 4; ++j)
        acc[i][j] = __builtin_amdgcn_mfma_f32_16x16x32_f16(a[i], b[j], acc[i][j], 0, 0, 0);
  }
  int rq = (lane >> 4) * 4;
#pragma unroll
  for (int i = 0; i < 4; ++i)
#pragma unroll
    for (int j = 0; j < 4; ++j)
#pragma unroll
      for (int r = 0; r < 4; ++r) {
        int row = m0 + wm * 64 + i * 16 + rq + r;
        int col = n0 + wn * 64 + j * 16 + lr;
        unsafeAtomicAdd(&C[(size_t)row * N + col], acc[i][j][r]);
      }
}

// ---------------- per-head RMSNorm + RoPE (wave per row) ----------------
__global__ __launch_bounds__(256) void normrope_kernel(
    const _Float16* __restrict__ qkv, const float* __restrict__ qw,
    const float* __restrict__ kw, const int* __restrict__ positions,
    _Float16* __restrict__ qh, _Float16* __restrict__ khb) {
  int wid = blockIdx.x * 4 + (threadIdx.x >> 6);
  int lane = threadIdx.x & 63;
  int t, hh;
  const _Float16* src;
  _Float16* dst;
  const float* w;
  if (wid < TT * NH) {
    t = wid >> 5; hh = wid & 31;
    src = qkv + (size_t)t * QKVNP + hh * HD;
    dst = qh + ((size_t)t * NH + hh) * HD;
    w = qw;
  } else {
    int r = wid - TT * NH;
    t = r >> 3; hh = r & 7;
    src = qkv + (size_t)t * QKVNP + QSIZE + hh * HD;
    dst = khb + ((size_t)t * NKV + hh) * HD;
    w = kw;
  }
  float x1 = (float)src[lane];
  float x2 = (float)src[lane + 64];
  float ss = x1 * x1 + x2 * x2;
#pragma unroll
  for (int off = 1; off < 64; off <<= 1) ss += __shfl_xor(ss, off);
  float rr = rsqrtf(ss * (1.0f / 128.0f) + 1e-6f);
  float n1 = x1 * rr * w[lane];
  float n2 = x2 * rr * w[lane + 64];
  float pos = (float)positions[t];
  float invf = exp2f(-(float)lane * (13.287712379549449f / 64.0f));  // 10000^(-lane/64)
  float ang = pos * invf;
  float sn, cs;
  sincosf(ang, &sn, &cs);
  dst[lane] = (_Float16)(n1 * cs - n2 * sn);
  dst[lane + 64] = (_Float16)(n2 * cs + n1 * sn);
}

// ---------------- MFMA sliding-window attention, barrier-free ----------------
// block = (32 q-rows, kv-head); wave w = q-head kh*4+w, 2 m-tiles of 16.
// Fixed softmax max M0 (scores provably |s|<=11.3): no online-softmax rescaling.
#define PSTR 68
#define M0 8.0f
__global__ __launch_bounds__(256, 2) void attn_kernel(
    const _Float16* __restrict__ Qh, const _Float16* __restrict__ Kf,
    const _Float16* __restrict__ Vf, const _Float16* __restrict__ QKVh,
    _Float16* __restrict__ Og) {
  const float scale = 0.08838834764831845f;  // 128^-0.5
  __shared__ _Float16 Ps[4][2 * 16 * PSTR];
  int tid = threadIdx.x;
  int wave = tid >> 6, lane = tid & 63;
  int n16 = lane & 15, quad = lane >> 4;
  int t0 = blockIdx.x * 32;
  int kh = blockIdx.y;
  int h = kh * 4 + wave;
  _Float16* ps = Ps[wave];

  half8 qf[2][4];
#pragma unroll
  for (int mt = 0; mt < 2; ++mt)
#pragma unroll
    for (int kc = 0; kc < 4; ++kc)
      qf[mt][kc] = *(const half8*)&Qh[((size_t)(t0 + mt * 16 + n16) * NH + h) * HD +
                                      kc * 32 + quad * 8];

  floatx4 O[2][8];
  float lp[2][4];
#pragma unroll
  for (int mt = 0; mt < 2; ++mt) {
#pragma unroll
    for (int jd = 0; jd < 8; ++jd) O[mt][jd] = (floatx4){0.f, 0.f, 0.f, 0.f};
#pragma unroll
    for (int r = 0; r < 4; ++r) lp[mt][r] = 0.f;
  }

  int lo = t0 - (WINDOW - 1);
  if (lo < 0) lo = 0;
  int st1 = (t0 + 31) >> 6;
  for (int st = lo >> 6; st <= st1; ++st) {
    int s0 = st * 64;
    const _Float16* kb = Kf + (size_t)(kh * 32 + st) * 8192;
    const _Float16* vb = Vf + (size_t)(kh * 32 + st) * 8192;
    // ---- QK^T
    floatx4 S[2][4];
#pragma unroll
    for (int mt = 0; mt < 2; ++mt)
#pragma unroll
      for (int jt = 0; jt < 4; ++jt) S[mt][jt] = (floatx4){0.f, 0.f, 0.f, 0.f};
#pragma unroll
    for (int jt = 0; jt < 4; ++jt) {
      half8 kfr[4];
#pragma unroll
      for (int kc = 0; kc < 4; ++kc)
        kfr[kc] = *(const half8*)&kb[(jt * 4 + kc) * 512 + lane * 8];
#pragma unroll
      for (int kc = 0; kc < 4; ++kc)
#pragma unroll
        for (int mt = 0; mt < 2; ++mt)
          S[mt][jt] = __builtin_amdgcn_mfma_f32_16x16x32_f16(qf[mt][kc], kfr[kc], S[mt][jt], 0, 0, 0);
    }
    // ---- p = exp(s*scale - M0); masks only on boundary tiles
    bool interior = (t0 >= s0 + 63) && (t0 + 31 - s0 < WINDOW);
    if (interior) {
#pragma unroll
      for (int mt = 0; mt < 2; ++mt)
#pragma unroll
        for (int r = 0; r < 4; ++r) {
          float rs = 0.f;
#pragma unroll
          for (int jt = 0; jt < 4; ++jt) {
            float p = __expf(__builtin_fmaf(S[mt][jt][r], scale, -M0));
            rs += p;
            ps[(mt * 16 + quad * 4 + r) * PSTR + jt * 16 + n16] = (_Float16)p;
          }
          lp[mt][r] += rs;
        }
    } else {
#pragma unroll
      for (int mt = 0; mt < 2; ++mt)
#pragma unroll
        for (int r = 0; r < 4; ++r) {
          int tq = t0 + mt * 16 + quad * 4 + r;
          float rs = 0.f;
#pragma unroll
          for (int jt = 0; jt < 4; ++jt) {
            int diff = tq - (s0 + jt * 16 + n16);
            bool ok = (diff >= 0) && (diff < WINDOW);
            float p = ok ? __expf(__builtin_fmaf(S[mt][jt][r], scale, -M0)) : 0.f;
            rs += p;
            ps[(mt * 16 + quad * 4 + r) * PSTR + jt * 16 + n16] = (_Float16)p;
          }
          lp[mt][r] += rs;
        }
    }
    // ---- P: C-layout -> A-layout via wave-private LDS (in-order DS pipe)
    half8 pf[2][2];
#pragma unroll
    for (int mt = 0; mt < 2; ++mt)
#pragma unroll
      for (int kc = 0; kc < 2; ++kc) {
        half4 lo4 = *(const half4*)&ps[(mt * 16 + n16) * PSTR + kc * 32 + quad * 8];
        half4 hi4 = *(const half4*)&ps[(mt * 16 + n16) * PSTR + kc * 32 + quad * 8 + 4];
        pf[mt][kc] = (half8){lo4[0], lo4[1], lo4[2], lo4[3], hi4[0], hi4[1], hi4[2], hi4[3]};
      }
    // ---- PV
#pragma unroll
    for (int jd = 0; jd < 8; ++jd) {
#pragma unroll
      for (int kc = 0; kc < 2; ++kc) {
        half8 vfr = *(const half8*)&vb[(jd * 2 + kc) * 512 + lane * 8];
#pragma unroll
        for (int mt = 0; mt < 2; ++mt)
          O[mt][jd] = __builtin_amdgcn_mfma_f32_16x16x32_f16(pf[mt][kc], vfr, O[mt][jd], 0, 0, 0);
      }
    }
  }
  // ---- epilogue: reduce l, softplus gate, normalize, store
#pragma unroll
  for (int mt = 0; mt < 2; ++mt)
#pragma unroll
    for (int r = 0; r < 4; ++r) {
      float l = lp[mt][r];
#pragma unroll
      for (int off = 1; off < 16; off <<= 1) l += __shfl_xor(l, off);
      int t = t0 + mt * 16 + quad * 4 + r;
      float gl = (float)QKVh[(size_t)t * QKVNP + GOFF + h];
      float g = (gl > 0.f) ? gl + log1pf(__expf(-gl)) : log1pf(__expf(gl));
      float inv = g / l;
#pragma unroll
      for (int jd = 0; jd < 8; ++jd)
        Og[(size_t)t * QSIZE + h * HD + jd * 16 + n16] = (_Float16)(O[mt][jd][r] * inv);
    }
}

// ---------------- launcher ----------------
extern "C" void kernel_launch(void* const* d_in, const int* in_sizes, int n_in,
                              void* d_out, int out_size, void* d_ws, size_t ws_size,
                              hipStream_t stream) {
  const int* positions = (const int*)d_in[0];
  const float* hidden = (const float*)d_in[1];
  const float* w_qkv = (const float*)d_in[2];
  const float* w_o = (const float*)d_in[3];
  const float* w_g = (const float*)d_in[4];
  const float* q_norm_w = (const float*)d_in[5];
  const float* k_norm_w = (const float*)d_in[6];
  float* out = (float*)d_out;

  char* ws = (char*)d_ws;
  size_t off = 0;
  auto alloc = [&](size_t bytes) {
    void* p = ws + off;
    off += (bytes + 255) & ~(size_t)255;
    return p;
  };
  _Float16* Xb = (_Float16*)alloc((size_t)TT * HIDDEN * 2);
  _Float16* Wqkvt = (_Float16*)alloc((size_t)QKVNP * HIDDEN * 2);
  _Float16* Wot = (_Float16*)alloc((size_t)HIDDEN * QSIZE * 2);
  _Float16* QKVh = (_Float16*)alloc((size_t)TT * QKVNP * 2);
  _Float16* Qh = (_Float16*)alloc((size_t)TT * NH * HD * 2);
  _Float16* Kh = (_Float16*)alloc((size_t)TT * NKV * HD * 2);
  _Float16* Kf = (_Float16*)alloc((size_t)NKV * 32 * 8192 * 2);
  _Float16* Vf = (_Float16*)alloc((size_t)NKV * 32 * 8192 * 2);
  _Float16* Og = (_Float16*)alloc((size_t)TT * QSIZE * 2);

  // zero pad rows of Wqkvt (6176..6271) and the atomic-accumulated output
  hipMemsetAsync(Wqkvt + (size_t)(GOFF + NH) * HIDDEN, 0, (size_t)96 * HIDDEN * 2, stream);
  hipMemsetAsync(d_out, 0, (size_t)out_size * 4, stream);

  cvt_f32_f16_kernel<<<(TT * HIDDEN) / 1024, 256, 0, stream>>>(hidden, Xb);
  transpose_f32_f16_kernel<<<dim3(QKVN / 32, HIDDEN / 32), 256, 0, stream>>>(w_qkv, Wqkvt,
                                                                             HIDDEN, QKVN);
  transpose_f32_f16_kernel<<<dim3(1, HIDDEN / 32), 256, 0, stream>>>(
      w_g, Wqkvt + (size_t)GOFF * HIDDEN, HIDDEN, NH);
  transpose_f32_f16_kernel<<<dim3(HIDDEN / 32, QSIZE / 32), 256, 0, stream>>>(w_o, Wot, QSIZE,
                                                                              HIDDEN);
  gemm_bt_kernel<_Float16><<<dim3(QKVNP / 128, TT / 128), 256, 0, stream>>>(
      Xb, Wqkvt, QKVh, TT, QKVNP, HIDDEN);
  normrope_kernel<<<(TT * (NH + NKV)) / 4, 256, 0, stream>>>(QKVh, q_norm_w, k_norm_w,
                                                             positions, Qh, Kh);
  repack_k_kernel<<<dim3(32, NKV), 256, 0, stream>>>(Kh, Kf);
  repack_v_kernel<<<dim3(32, NKV), 256, 0, stream>>>(QKVh, Vf);
  attn_kernel<<<dim3(TT / 32, NKV), 256, 0, stream>>>(Qh, Kf, Vf, QKVh, Og);
  gemm_bt_splitk_kernel<<<dim3(HIDDEN / 128, TT / 128, 2), 256, 0, stream>>>(
      Og, Wot, out, TT, HIDDEN, QSIZE, QSIZE / 2);
}

// Round 5
// 369.807 us; speedup vs baseline: 1.9568x; 1.0279x over previous
//
#include <hip/hip_runtime.h>

typedef __attribute__((ext_vector_type(4))) float floatx4;
typedef __attribute__((ext_vector_type(8))) _Float16 half8;
typedef __attribute__((ext_vector_type(4))) _Float16 half4;

#define TT 2048
#define HIDDEN 2048
#define NH 32
#define NKV 8
#define HD 128
#define QSIZE 4096
#define KVSIZE 1024
#define QKVN 6144
#define QKVNP 6272   // padded: +32 gate cols +96 zero
#define VOFF 5120
#define GOFF 6144
#define WINDOW 512

// ---------------- unified prep: w_qkv^T, w_o^T (64x64 tiles), cvt, pad-zero ----
// blocks [0,3072): w_qkv 2048x6144 -> Wqkvt ; [3072,5120): w_o 4096x2048 -> Wot ;
// [5120,7168): hidden fp32->fp16 ; [7168,7264): zero pad rows of Wqkvt.
__global__ __launch_bounds__(256) void prep_kernel(
    const float* __restrict__ w_qkv, const float* __restrict__ w_o,
    const float* __restrict__ hidden, _Float16* __restrict__ Wqkvt,
    _Float16* __restrict__ Wot, _Float16* __restrict__ Xb) {
  __shared__ float tile[64][68];  // 272B rows: 16B-aligned float4 slots
  int bid = blockIdx.x;
  int tid = threadIdx.x;
  if (bid >= 5120) {
    if (bid < 7168) {
      int i = ((bid - 5120) * 256 + tid) * 8;
      float4 a = *(const float4*)&hidden[i];
      float4 b = *(const float4*)&hidden[i + 4];
      alignas(16) _Float16 o[8] = {(_Float16)a.x, (_Float16)a.y, (_Float16)a.z, (_Float16)a.w,
                                   (_Float16)b.x, (_Float16)b.y, (_Float16)b.z, (_Float16)b.w};
      *(uint4*)&Xb[i] = *(const uint4*)o;
    } else {
      int i = ((bid - 7168) * 256 + tid) * 8;
      *(uint4*)&Wqkvt[(size_t)(GOFF + NH) * HIDDEN + i] = (uint4){0, 0, 0, 0};
    }
    return;
  }
  const float* in;
  _Float16* out;
  int R, C, tilesX, t;
  if (bid < 3072) { in = w_qkv; out = Wqkvt; R = HIDDEN; C = QKVN; tilesX = 96; t = bid; }
  else           { in = w_o;   out = Wot;   R = QSIZE;  C = HIDDEN; tilesX = 32; t = bid - 3072; }
  int bc = (t % tilesX) * 64, br = (t / tilesX) * 64;
  int rr = tid >> 4, l16 = tid & 15;
#pragma unroll
  for (int it = 0; it < 4; ++it) {
    int r = rr + it * 16;
    *(float4*)&tile[r][l16 * 4] = *(const float4*)&in[(size_t)(br + r) * C + bc + l16 * 4];
  }
  __syncthreads();
  int orow = tid >> 2, rr0 = (tid & 3) * 16;
  alignas(16) _Float16 tmp[16];
#pragma unroll
  for (int jj = 0; jj < 16; ++jj) tmp[jj] = (_Float16)tile[rr0 + jj][orow];
  *(uint4*)&out[(size_t)(bc + orow) * R + br + rr0] = *(const uint4*)&tmp[0];
  *(uint4*)&out[(size_t)(bc + orow) * R + br + rr0 + 8] = *(const uint4*)&tmp[8];
}

// ---------------- fp32 [R][C] -> fp16 [C][R] transpose (small, for w_g) --------
__global__ __launch_bounds__(256) void transpose_f32_f16_kernel(
    const float* __restrict__ in, _Float16* __restrict__ out, int R, int C) {
  __shared__ float tile[32][33];
  int bc = blockIdx.x * 32;
  int br = blockIdx.y * 32;
  int c = threadIdx.x & 31;
  int r0 = threadIdx.x >> 5;
#pragma unroll
  for (int i = 0; i < 4; ++i) {
    int r = r0 + 8 * i;
    tile[r][c] = in[(size_t)(br + r) * C + bc + c];
  }
  __syncthreads();
#pragma unroll
  for (int i = 0; i < 4; ++i) {
    int r = r0 + 8 * i;
    out[(size_t)(bc + r) * R + br + c] = (_Float16)tile[c][r];
  }
}

// ---------------- K/V -> fragment-linear repack (z=0: K, z=1: V) -------------
__global__ __launch_bounds__(256) void repack_kv_kernel(const _Float16* __restrict__ Kh,
                                                        const _Float16* __restrict__ QKVh,
                                                        _Float16* __restrict__ Kf,
                                                        _Float16* __restrict__ Vf) {
  __shared__ _Float16 tile[64][136];
  int st = blockIdx.x, kh = blockIdx.y;
  int s0 = st * 64;
  if (blockIdx.z == 0) {
    _Float16* dst = Kf + (size_t)(kh * 32 + st) * 8192;
#pragma unroll
    for (int i = 0; i < 4; ++i) {
      int c = threadIdx.x + i * 256;  // c = jt*256 + kc*64 + quad*16 + n16
      int jt = c >> 8, kc = (c >> 6) & 3, quad = (c >> 4) & 3, n16 = c & 15;
      uint4 v = *(const uint4*)&Kh[((size_t)(s0 + jt * 16 + n16) * NKV + kh) * HD +
                                   kc * 32 + quad * 8];
      *(uint4*)&dst[c * 8] = v;
    }
  } else {
#pragma unroll
    for (int i = 0; i < 4; ++i) {
      int c = threadIdx.x + i * 256;  // c = row*16 + part
      int row = c >> 4, part = c & 15;
      *(uint4*)&tile[row][part * 8] =
          *(const uint4*)&QKVh[(size_t)(s0 + row) * QKVNP + VOFF + kh * HD + part * 8];
    }
    __syncthreads();
    _Float16* dst = Vf + (size_t)(kh * 32 + st) * 8192;
#pragma unroll
    for (int i = 0; i < 4; ++i) {
      int c = threadIdx.x + i * 256;  // c = jd*128 + kc*64 + quad*16 + n16
      int jd = c >> 7, kc = (c >> 6) & 1, quad = (c >> 4) & 3, n16 = c & 15;
      int d = jd * 16 + n16, sb = kc * 32 + quad * 8;
      alignas(16) _Float16 tmp[8];
#pragma unroll
      for (int j = 0; j < 8; ++j) tmp[j] = tile[sb + j][d];
      *(uint4*)&dst[c * 8] = *(const uint4*)tmp;
    }
  }
}

// ---------------- async 16B global->LDS (wave-uniform LDS base + lane*16) -------
__device__ __forceinline__ void async16(const _Float16* g, _Float16* l) {
  __builtin_amdgcn_global_load_lds((const __attribute__((address_space(1))) void*)g,
                                   (__attribute__((address_space(3))) void*)l, 16, 0, 0);
}

// band swizzle: grid(x=mtiles, y=ntiles); 8 m-tiles x all-n bands so consecutive
// blocks share B tiles and a band's A set (4MB) fits per-XCD L2.
__device__ __forceinline__ void swizzle_mn(int& m0, int& n0) {
  int ntiles = gridDim.y;
  int pid = blockIdx.x + blockIdx.y * gridDim.x;
  int band = pid / (8 * ntiles);
  int wi = pid - band * (8 * ntiles);
  m0 = (band * 8 + (wi & 7)) * 128;
  n0 = (wi >> 3) * 128;
}

// ---------------- MFMA GEMM: C[M][N] = A[M][K] * Bt[N][K]^T ----------------
template <typename OutT>
__global__ __launch_bounds__(256, 2) void gemm_bt_kernel(
    const _Float16* __restrict__ A, const _Float16* __restrict__ Bt,
    OutT* __restrict__ C, int M, int N, int K) {
  __shared__ _Float16 As[128 * 32];
  __shared__ _Float16 Bs[128 * 32];
  int tid = threadIdx.x;
  int wave = tid >> 6, lane = tid & 63;
  int wm = wave >> 1, wn = wave & 1;
  int m0, n0;
  swizzle_mn(m0, n0);
  int lr = lane & 15;
  int kq = (lane >> 4) * 8;
  floatx4 acc[4][4];
#pragma unroll
  for (int i = 0; i < 4; ++i)
#pragma unroll
    for (int j = 0; j < 4; ++j) acc[i][j] = (floatx4){0.f, 0.f, 0.f, 0.f};

  for (int k0 = 0; k0 < K; k0 += 32) {
    __syncthreads();
#pragma unroll
    for (int it = 0; it < 2; ++it) {
      int c = tid + it * 256;
      int row = c >> 2, kp = (c & 3) * 8;
      _Float16* la = &As[it * 2048 + wave * 512];
      _Float16* lb = &Bs[it * 2048 + wave * 512];
      async16(&A[(size_t)(m0 + row) * K + k0 + kp], la);
      async16(&Bt[(size_t)(n0 + row) * K + k0 + kp], lb);
    }
    __syncthreads();
    half8 a[4], b[4];
#pragma unroll
    for (int i = 0; i < 4; ++i) a[i] = *(const half8*)&As[(wm * 64 + i * 16 + lr) * 32 + kq];
#pragma unroll
    for (int j = 0; j < 4; ++j) b[j] = *(const half8*)&Bs[(wn * 64 + j * 16 + lr) * 32 + kq];
#pragma unroll
    for (int i = 0; i < 4; ++i)
#pragma unroll
      for (int j = 0; j < 4; ++j)
        acc[i][j] = __builtin_amdgcn_mfma_f32_16x16x32_f16(a[i], b[j], acc[i][j], 0, 0, 0);
  }
  int rq = (lane >> 4) * 4;
#pragma unroll
  for (int i = 0; i < 4; ++i)
#pragma unroll
    for (int j = 0; j < 4; ++j)
#pragma unroll
      for (int r = 0; r < 4; ++r) {
        int row = m0 + wm * 64 + i * 16 + rq + r;
        int col = n0 + wn * 64 + j * 16 + lr;
        C[(size_t)row * N + col] = (OutT)acc[i][j][r];
      }
}

// ---------------- split-K MFMA GEMM, fp32 atomic epilogue --------------------
__global__ __launch_bounds__(256, 2) void gemm_bt_splitk_kernel(
    const _Float16* __restrict__ A, const _Float16* __restrict__ Bt,
    float* __restrict__ C, int M, int N, int K, int Ks) {
  __shared__ _Float16 As[128 * 32];
  __shared__ _Float16 Bs[128 * 32];
  int tid = threadIdx.x;
  int wave = tid >> 6, lane = tid & 63;
  int wm = wave >> 1, wn = wave & 1;
  int m0, n0;
  swizzle_mn(m0, n0);
  int kb = blockIdx.z * Ks;
  int lr = lane & 15;
  int kq = (lane >> 4) * 8;
  floatx4 acc[4][4];
#pragma unroll
  for (int i = 0; i < 4; ++i)
#pragma unroll
    for (int j = 0; j < 4; ++j) acc[i][j] = (floatx4){0.f, 0.f, 0.f, 0.f};

  for (int k0 = kb; k0 < kb + Ks; k0 += 32) {
    __syncthreads();
#pragma unroll
    for (int it = 0; it < 2; ++it) {
      int c = tid + it * 256;
      int row = c >> 2, kp = (c & 3) * 8;
      _Float16* la = &As[it * 2048 + wave * 512];
      _Float16* lb = &Bs[it * 2048 + wave * 512];
      async16(&A[(size_t)(m0 + row) * K + k0 + kp], la);
      async16(&Bt[(size_t)(n0 + row) * K + k0 + kp], lb);
    }
    __syncthreads();
    half8 a[4], b[4];
#pragma unroll
    for (int i = 0; i < 4; ++i) a[i] = *(const half8*)&As[(wm * 64 + i * 16 + lr) * 32 + kq];
#pragma unroll
    for (int j = 0; j < 4; ++j) b[j] = *(const half8*)&Bs[(wn * 64 + j * 16 + lr) * 32 + kq];
#pragma unroll
    for (int i = 0; i < 4; ++i)
#pragma unroll
      for (int j = 0; j < 4; ++j)
        acc[i][j] = __builtin_amdgcn_mfma_f32_16x16x32_f16(a[i], b[j], acc[i][j], 0, 0, 0);
  }
  int rq = (lane >> 4) * 4;
#pragma unroll
  for (int i = 0; i < 4; ++i)
#pragma unroll
    for (int j = 0; j < 4; ++j)
#pragma unroll
      for (int r = 0; r < 4; ++r) {
        int row = m0 + wm * 64 + i * 16 + rq + r;
        int col = n0 + wn * 64 + j * 16 + lr;
        unsafeAtomicAdd(&C[(size_t)row * N + col], acc[i][j][r]);
      }
}

// ---------------- per-head RMSNorm + RoPE (wave per row) ----------------
__global__ __launch_bounds__(256) void normrope_kernel(
    const _Float16* __restrict__ qkv, const float* __restrict__ qw,
    const float* __restrict__ kw, const int* __restrict__ positions,
    _Float16* __restrict__ qh, _Float16* __restrict__ khb) {
  int wid = blockIdx.x * 4 + (threadIdx.x >> 6);
  int lane = threadIdx.x & 63;
  int t, hh;
  const _Float16* src;
  _Float16* dst;
  const float* w;
  if (wid < TT * NH) {
    t = wid >> 5; hh = wid & 31;
    src = qkv + (size_t)t * QKVNP + hh * HD;
    dst = qh + ((size_t)t * NH + hh) * HD;
    w = qw;
  } else {
    int r = wid - TT * NH;
    t = r >> 3; hh = r & 7;
    src = qkv + (size_t)t * QKVNP + QSIZE + hh * HD;
    dst = khb + ((size_t)t * NKV + hh) * HD;
    w = kw;
  }
  float x1 = (float)src[lane];
  float x2 = (float)src[lane + 64];
  float ss = x1 * x1 + x2 * x2;
#pragma unroll
  for (int off = 1; off < 64; off <<= 1) ss += __shfl_xor(ss, off);
  float rr = rsqrtf(ss * (1.0f / 128.0f) + 1e-6f);
  float n1 = x1 * rr * w[lane];
  float n2 = x2 * rr * w[lane + 64];
  float pos = (float)positions[t];
  float invf = exp2f(-(float)lane * (13.287712379549449f / 64.0f));  // 10000^(-lane/64)
  float ang = pos * invf;
  float sn, cs;
  sincosf(ang, &sn, &cs);
  dst[lane] = (_Float16)(n1 * cs - n2 * sn);
  dst[lane + 64] = (_Float16)(n2 * cs + n1 * sn);
}

// ---------------- MFMA sliding-window attention, barrier-free ----------------
#define PSTR 68
#define M0 8.0f
__global__ __launch_bounds__(256, 2) void attn_kernel(
    const _Float16* __restrict__ Qh, const _Float16* __restrict__ Kf,
    const _Float16* __restrict__ Vf, const _Float16* __restrict__ QKVh,
    _Float16* __restrict__ Og) {
  const float scale = 0.08838834764831845f;  // 128^-0.5
  __shared__ _Float16 Ps[4][2 * 16 * PSTR];
  int tid = threadIdx.x;
  int wave = tid >> 6, lane = tid & 63;
  int n16 = lane & 15, quad = lane >> 4;
  int t0 = blockIdx.x * 32;
  int kh = blockIdx.y;
  int h = kh * 4 + wave;
  _Float16* ps = Ps[wave];

  half8 qf[2][4];
#pragma unroll
  for (int mt = 0; mt < 2; ++mt)
#pragma unroll
    for (int kc = 0; kc < 4; ++kc)
      qf[mt][kc] = *(const half8*)&Qh[((size_t)(t0 + mt * 16 + n16) * NH + h) * HD +
                                      kc * 32 + quad * 8];

  floatx4 O[2][8];
  float lp[2][4];
#pragma unroll
  for (int mt = 0; mt < 2; ++mt) {
#pragma unroll
    for (int jd = 0; jd < 8; ++jd) O[mt][jd] = (floatx4){0.f, 0.f, 0.f, 0.f};
#pragma unroll
    for (int r = 0; r < 4; ++r) lp[mt][r] = 0.f;
  }

  int lo = t0 - (WINDOW - 1);
  if (lo < 0) lo = 0;
  int st1 = (t0 + 31) >> 6;
  for (int st = lo >> 6; st <= st1; ++st) {
    int s0 = st * 64;
    const _Float16* kb = Kf + (size_t)(kh * 32 + st) * 8192;
    const _Float16* vb = Vf + (size_t)(kh * 32 + st) * 8192;
    floatx4 S[2][4];
#pragma unroll
    for (int mt = 0; mt < 2; ++mt)
#pragma unroll
      for (int jt = 0; jt < 4; ++jt) S[mt][jt] = (floatx4){0.f, 0.f, 0.f, 0.f};
#pragma unroll
    for (int jt = 0; jt < 4; ++jt) {
      half8 kfr[4];
#pragma unroll
      for (int kc = 0; kc < 4; ++kc)
        kfr[kc] = *(const half8*)&kb[(jt * 4 + kc) * 512 + lane * 8];
#pragma unroll
      for (int kc = 0; kc < 4; ++kc)
#pragma unroll
        for (int mt = 0; mt < 2; ++mt)
          S[mt][jt] = __builtin_amdgcn_mfma_f32_16x16x32_f16(qf[mt][kc], kfr[kc], S[mt][jt], 0, 0, 0);
    }
    bool interior = (t0 >= s0 + 63) && (t0 + 31 - s0 < WINDOW);
    if (interior) {
#pragma unroll
      for (int mt = 0; mt < 2; ++mt)
#pragma unroll
        for (int r = 0; r < 4; ++r) {
          float rs = 0.f;
#pragma unroll
          for (int jt = 0; jt < 4; ++jt) {
            float p = __expf(__builtin_fmaf(S[mt][jt][r], scale, -M0));
            rs += p;
            ps[(mt * 16 + quad * 4 + r) * PSTR + jt * 16 + n16] = (_Float16)p;
          }
          lp[mt][r] += rs;
        }
    } else {
#pragma unroll
      for (int mt = 0; mt < 2; ++mt)
#pragma unroll
        for (int r = 0; r < 4; ++r) {
          int tq = t0 + mt * 16 + quad * 4 + r;
          float rs = 0.f;
#pragma unroll
          for (int jt = 0; jt < 4; ++jt) {
            int diff = tq - (s0 + jt * 16 + n16);
            bool ok = (diff >= 0) && (diff < WINDOW);
            float p = ok ? __expf(__builtin_fmaf(S[mt][jt][r], scale, -M0)) : 0.f;
            rs += p;
            ps[(mt * 16 + quad * 4 + r) * PSTR + jt * 16 + n16] = (_Float16)p;
          }
          lp[mt][r] += rs;
        }
    }
    half8 pf[2][2];
#pragma unroll
    for (int mt = 0; mt < 2; ++mt)
#pragma unroll
      for (int kc = 0; kc < 2; ++kc) {
        half4 lo4 = *(const half4*)&ps[(mt * 16 + n16) * PSTR + kc * 32 + quad * 8];
        half4 hi4 = *(const half4*)&ps[(mt * 16 + n16) * PSTR + kc * 32 + quad * 8 + 4];
        pf[mt][kc] = (half8){lo4[0], lo4[1], lo4[2], lo4[3], hi4[0], hi4[1], hi4[2], hi4[3]};
      }
#pragma unroll
    for (int jd = 0; jd < 8; ++jd) {
#pragma unroll
      for (int kc = 0; kc < 2; ++kc) {
        half8 vfr = *(const half8*)&vb[(jd * 2 + kc) * 512 + lane * 8];
#pragma unroll
        for (int mt = 0; mt < 2; ++mt)
          O[mt][jd] = __builtin_amdgcn_mfma_f32_16x16x32_f16(pf[mt][kc], vfr, O[mt][jd], 0, 0, 0);
      }
    }
  }
#pragma unroll
  for (int mt = 0; mt < 2; ++mt)
#pragma unroll
    for (int r = 0; r < 4; ++r) {
      float l = lp[mt][r];
#pragma unroll
      for (int off = 1; off < 16; off <<= 1) l += __shfl_xor(l, off);
      int t = t0 + mt * 16 + quad * 4 + r;
      float gl = (float)QKVh[(size_t)t * QKVNP + GOFF + h];
      float g = (gl > 0.f) ? gl + log1pf(__expf(-gl)) : log1pf(__expf(gl));
      float inv = g / l;
#pragma unroll
      for (int jd = 0; jd < 8; ++jd)
        Og[(size_t)t * QSIZE + h * HD + jd * 16 + n16] = (_Float16)(O[mt][jd][r] * inv);
    }
}

// ---------------- launcher ----------------
extern "C" void kernel_launch(void* const* d_in, const int* in_sizes, int n_in,
                              void* d_out, int out_size, void* d_ws, size_t ws_size,
                              hipStream_t stream) {
  const int* positions = (const int*)d_in[0];
  const float* hidden = (const float*)d_in[1];
  const float* w_qkv = (const float*)d_in[2];
  const float* w_o = (const float*)d_in[3];
  const float* w_g = (const float*)d_in[4];
  const float* q_norm_w = (const float*)d_in[5];
  const float* k_norm_w = (const float*)d_in[6];
  float* out = (float*)d_out;

  char* ws = (char*)d_ws;
  size_t off = 0;
  auto alloc = [&](size_t bytes) {
    void* p = ws + off;
    off += (bytes + 255) & ~(size_t)255;
    return p;
  };
  _Float16* Xb = (_Float16*)alloc((size_t)TT * HIDDEN * 2);
  _Float16* Wqkvt = (_Float16*)alloc((size_t)QKVNP * HIDDEN * 2);
  _Float16* Wot = (_Float16*)alloc((size_t)HIDDEN * QSIZE * 2);
  _Float16* QKVh = (_Float16*)alloc((size_t)TT * QKVNP * 2);
  _Float16* Qh = (_Float16*)alloc((size_t)TT * NH * HD * 2);
  _Float16* Kh = (_Float16*)alloc((size_t)TT * NKV * HD * 2);
  _Float16* Kf = (_Float16*)alloc((size_t)NKV * 32 * 8192 * 2);
  _Float16* Vf = (_Float16*)alloc((size_t)NKV * 32 * 8192 * 2);
  _Float16* Og = (_Float16*)alloc((size_t)TT * QSIZE * 2);

  hipMemsetAsync(d_out, 0, (size_t)out_size * 4, stream);

  prep_kernel<<<7264, 256, 0, stream>>>(w_qkv, w_o, hidden, Wqkvt, Wot, Xb);
  transpose_f32_f16_kernel<<<dim3(1, HIDDEN / 32), 256, 0, stream>>>(
      w_g, Wqkvt + (size_t)GOFF * HIDDEN, HIDDEN, NH);
  gemm_bt_kernel<_Float16><<<dim3(TT / 128, QKVNP / 128), 256, 0, stream>>>(
      Xb, Wqkvt, QKVh, TT, QKVNP, HIDDEN);
  normrope_kernel<<<(TT * (NH + NKV)) / 4, 256, 0, stream>>>(QKVh, q_norm_w, k_norm_w,
                                                             positions, Qh, Kh);
  repack_kv_kernel<<<dim3(32, NKV, 2), 256, 0, stream>>>(Kh, QKVh, Kf, Vf);
  attn_kernel<<<dim3(TT / 32, NKV), 256, 0, stream>>>(Qh, Kf, Vf, QKVh, Og);
  gemm_bt_splitk_kernel<<<dim3(TT / 128, HIDDEN / 128, 2), 256, 0, stream>>>(
      Og, Wot, out, TT, HIDDEN, QSIZE, QSIZE / 2);
}